// Round 2
// baseline (13102.913 us; speedup 1.0000x reference)
//
#include <hip/hip_runtime.h>
#include <hip/hip_bf16.h>
#include <stdint.h>

typedef unsigned int u32;
typedef unsigned short u16;

#define NPTS 524288
#define FF 4
#define HH 64
#define WW 512
#define SS 262144
#define EPSV 1e-5f

__device__ __forceinline__ float bf2f(u16 h){ return __uint_as_float(((u32)h)<<16); }
__device__ __forceinline__ u16 f2bf(float f){
  u32 u = __float_as_uint(f);
  return (u16)((u + 0x7FFFu + ((u>>16)&1u)) >> 16);   // RNE
}
// monotone f32 <-> u32 key for atomicMax-based float max
__device__ __forceinline__ u32 fkey(float f){
  u32 u = __float_as_uint(f);
  return u ^ ((u32)(((int)u) >> 31) | 0x80000000u);
}
__device__ __forceinline__ float fdec(u32 k){
  u32 u = (k & 0x80000000u) ? (k ^ 0x80000000u) : ~k;
  return __uint_as_float(u);
}

// ---------------- shared chain pieces ----------------
__device__ __forceinline__ void point_feats(int p, const float* __restrict__ pts,
    const u32* __restrict__ lin, const u32* __restrict__ counts,
    const float* __restrict__ vsum, float f[8], u32* vout){
  float4 pt = ((const float4*)pts)[p];
  u32 v = lin[p];
  float cnt = fmaxf((float)counts[v], 1.0f);
  float inv = 1.0f/cnt;
  float mx = vsum[v*3+0]*inv, my = vsum[v*3+1]*inv, mz = vsum[v*3+2]*inv;
  float dist = sqrtf(pt.x*pt.x + pt.y*pt.y + pt.z*pt.z);
  f[0]=pt.x; f[1]=pt.y; f[2]=pt.z; f[3]=pt.w; f[4]=dist;
  f[5]=pt.x-mx; f[6]=pt.y-my; f[7]=pt.z-mz;
  *vout = v;
}

// acc[0..63] += row(bf16 pairs, swizzled) @ W[2k..][jbase..jbase+63]
__device__ __forceinline__ void row_gemm64(const u32* row, int sw, int kPairs,
    const float* __restrict__ W, int ldw, int jbase, float acc[64]){
  for(int kk=0; kk<kPairs; ++kk){
    u32 pr = row[kk ^ sw];
    float e0 = bf2f((u16)(pr & 0xFFFFu));
    float e1 = bf2f((u16)(pr >> 16));
    const float* w0 = W + (size_t)(2*kk)*ldw + jbase;
    const float* w1 = w0 + ldw;
    #pragma unroll
    for(int j=0;j<64;j++) acc[j] += e0*w0[j] + e1*w1[j];
  }
}

// feats -> bn0 -> z1 -> bnrelu1 -> y1 packed (bf16) into row words [0,32)
__device__ __forceinline__ void chain_y1_row(int p, int sw, u32* row,
    const float* __restrict__ pts, const u32* __restrict__ lin,
    const u32* __restrict__ counts, const float* __restrict__ vsum,
    const float* __restrict__ a0, const float* __restrict__ c0,
    const float* __restrict__ a1, const float* __restrict__ c1,
    const float* __restrict__ W1, u32* vout){
  float f[8]; point_feats(p, pts, lin, counts, vsum, f, vout);
  float y0[8];
  #pragma unroll
  for(int k=0;k<8;k++) y0[k] = a0[k]*f[k] + c0[k];
  #pragma unroll
  for(int jj=0;jj<32;jj++){
    float s0=0.f, s1=0.f;
    #pragma unroll
    for(int k=0;k<8;k++){ s0 += y0[k]*W1[k*64+2*jj]; s1 += y0[k]*W1[k*64+2*jj+1]; }
    float v0f = fmaxf(a1[2*jj]*s0   + c1[2*jj],   0.f);
    float v1f = fmaxf(a1[2*jj+1]*s1 + c1[2*jj+1], 0.f);
    row[jj ^ sw] = (u32)f2bf(v0f) | ((u32)f2bf(v1f)<<16);
  }
}

// ... -> z2 -> bnrelu2 -> y2 packed (bf16) into row words [0,64)
__device__ __forceinline__ void chain_to_y2_row(int p, int sw, u32* row,
    const float* __restrict__ pts, const u32* __restrict__ lin,
    const u32* __restrict__ counts, const float* __restrict__ vsum,
    const float* __restrict__ a0, const float* __restrict__ c0,
    const float* __restrict__ a1, const float* __restrict__ c1,
    const float* __restrict__ a2, const float* __restrict__ c2,
    const float* __restrict__ W1, const float* __restrict__ W2, u32* vout){
  chain_y1_row(p, sw, row, pts, lin, counts, vsum, a0, c0, a1, c1, W1, vout);
  float y2[128];
  #pragma unroll
  for(int h=0;h<2;h++){
    float acc[64];
    #pragma unroll
    for(int j=0;j<64;j++) acc[j]=0.f;
    row_gemm64(row, sw, 32, W2, 128, h*64, acc);
    #pragma unroll
    for(int j=0;j<64;j++) y2[h*64+j] = fmaxf(a2[h*64+j]*acc[j] + c2[h*64+j], 0.f);
  }
  #pragma unroll
  for(int jj=0;jj<64;jj++)
    row[jj ^ sw] = (u32)f2bf(y2[2*jj]) | ((u32)f2bf(y2[2*jj+1])<<16);
}

// ---------------- pass 1: linear voxel id + counts + coord sums ----------------
__global__ __launch_bounds__(256) void k_lin(const float* __restrict__ pts,
                                             const int* __restrict__ coors,
                                             u32* __restrict__ lin,
                                             u32* __restrict__ counts,
                                             float* __restrict__ vsum){
  int p = blockIdx.x*256 + threadIdx.x;
  int4 c = ((const int4*)coors)[p];
  u32 v = ((u32)((c.x*FF + c.y)*HH + c.z))*WW + (u32)c.w;
  lin[p] = v;
  atomicAdd(&counts[v], 1u);
  float4 pt = ((const float4*)pts)[p];
  atomicAdd(&vsum[v*3+0], pt.x);
  atomicAdd(&vsum[v*3+1], pt.y);
  atomicAdd(&vsum[v*3+2], pt.z);
}

// ---------------- counting-sort scan ----------------
__global__ __launch_bounds__(256) void k_scan_a(const u32* __restrict__ counts,
                                                u32* __restrict__ blockSums){
  __shared__ u32 lds[256];
  int b = blockIdx.x, t = threadIdx.x;
  uint4 c4 = ((const uint4*)counts)[b*256 + t];
  lds[t] = c4.x + c4.y + c4.z + c4.w;
  __syncthreads();
  for(int s=128; s>0; s>>=1){ if(t<s) lds[t] += lds[t+s]; __syncthreads(); }
  if(t==0) blockSums[b] = lds[0];
}

__global__ void k_scan_b(u32* blockSums){
  if(threadIdx.x==0){
    u32 run = 0;
    for(int i=0;i<256;i++){ u32 v = blockSums[i]; blockSums[i] = run; run += v; }
  }
}

__global__ __launch_bounds__(256) void k_scan_c(const u32* __restrict__ counts,
                                                const u32* __restrict__ blockSums,
                                                u32* __restrict__ offsets,
                                                u32* __restrict__ cursor){
  __shared__ u32 lds[256];
  int b = blockIdx.x, t = threadIdx.x;
  uint4 c4 = ((const uint4*)counts)[b*256 + t];
  u32 mysum = c4.x + c4.y + c4.z + c4.w;
  lds[t] = mysum;
  __syncthreads();
  for(int d=1; d<256; d<<=1){
    u32 v = (t>=d) ? lds[t-d] : 0u;
    __syncthreads();
    lds[t] += v;
    __syncthreads();
  }
  u32 off = blockSums[b] + (t>0 ? lds[t-1] : 0u);
  u32 base = (u32)(b*1024 + t*4);
  offsets[base+0]=off; cursor[base+0]=off; off += c4.x;
  offsets[base+1]=off; cursor[base+1]=off; off += c4.y;
  offsets[base+2]=off; cursor[base+2]=off; off += c4.z;
  offsets[base+3]=off; cursor[base+3]=off; off += c4.w;
  if(base+4 == SS) offsets[SS] = off;
}

__global__ __launch_bounds__(256) void k_scatter(const u32* __restrict__ lin,
                                                 u32* __restrict__ cursor,
                                                 u32* __restrict__ order){
  int p = blockIdx.x*256 + threadIdx.x;
  u32 v = lin[p];
  u32 pos = atomicAdd(&cursor[v], 1u);
  order[pos] = p;
}

// ---------------- stats0: channel sums of raw feats ----------------
__global__ __launch_bounds__(256) void k_stats0(const float* __restrict__ pts,
    const u32* __restrict__ lin, const u32* __restrict__ counts,
    const float* __restrict__ vsum, float* __restrict__ sum0, float* __restrict__ sq0){
  int p = blockIdx.x*256 + threadIdx.x;
  float f[8]; u32 v;
  point_feats(p, pts, lin, counts, vsum, f, &v);
  __shared__ float lsum[4][8], lsq[4][8];
  int lane = threadIdx.x & 63, wv = threadIdx.x >> 6;
  #pragma unroll
  for(int c=0;c<8;c++){
    float s = f[c], q = f[c]*f[c];
    #pragma unroll
    for(int d=32; d; d>>=1){ s += __shfl_xor(s,d); q += __shfl_xor(q,d); }
    if(lane==0){ lsum[wv][c]=s; lsq[wv][c]=q; }
  }
  __syncthreads();
  if(threadIdx.x<8){
    float s=0.f,q=0.f;
    for(int g=0;g<4;g++){ s+=lsum[g][threadIdx.x]; q+=lsq[g][threadIdx.x]; }
    atomicAdd(&sum0[threadIdx.x], s);
    atomicAdd(&sq0[threadIdx.x], q);
  }
}

// ---------------- fold BN stats -> (a,c) ----------------
__global__ void k_fold(const float* __restrict__ sum, const float* __restrict__ sq,
                       const float* __restrict__ g, const float* __restrict__ b,
                       float* __restrict__ a, float* __restrict__ c, int C){
  int i = blockIdx.x*64 + threadIdx.x;
  if(i < C){
    float m = sum[i]*(1.0f/NPTS);
    float v = sq[i]*(1.0f/NPTS) - m*m;
    v = fmaxf(v, 0.0f);
    float ai = g[i] / sqrtf(v + EPSV);
    a[i] = ai;
    c[i] = b[i] - m*ai;
  }
}

// ---------------- stats1: channel sums of z1 (recomputed) ----------------
__global__ __launch_bounds__(256) void k_stats1(const float* __restrict__ pts,
    const u32* __restrict__ lin, const u32* __restrict__ counts,
    const float* __restrict__ vsum,
    const float* __restrict__ a0, const float* __restrict__ c0,
    const float* __restrict__ W1, float* __restrict__ sum1, float* __restrict__ sq1){
  __shared__ float ws[4][64], wq[4][64];
  int t = threadIdx.x;
  int p = blockIdx.x*256 + t;
  float f[8]; u32 v;
  point_feats(p, pts, lin, counts, vsum, f, &v);
  float y0[8];
  #pragma unroll
  for(int k=0;k<8;k++) y0[k] = a0[k]*f[k] + c0[k];
  float z[64];
  #pragma unroll
  for(int j=0;j<64;j++){
    float s=0.f;
    #pragma unroll
    for(int k=0;k<8;k++) s += y0[k]*W1[k*64+j];
    z[j]=s;
  }
  int lane = t&63, wv = t>>6;
  float ks=0.f, kq=0.f;
  #pragma unroll
  for(int c=0;c<64;c++){
    float s=z[c], q=z[c]*z[c];
    #pragma unroll
    for(int d=1; d<64; d<<=1){ s+=__shfl_xor(s,d); q+=__shfl_xor(q,d); }
    if(lane==c){ ks=s; kq=q; }
  }
  ws[wv][lane]=ks; wq[wv][lane]=kq;
  __syncthreads();
  if(t<64){
    float S=ws[0][t]+ws[1][t]+ws[2][t]+ws[3][t];
    float Q=wq[0][t]+wq[1][t]+wq[2][t]+wq[3][t];
    atomicAdd(&sum1[t],S); atomicAdd(&sq1[t],Q);
  }
}

// ---------------- stats2: channel sums of z2 (recomputed) ----------------
__global__ __launch_bounds__(256) void k_stats2(const float* __restrict__ pts,
    const u32* __restrict__ lin, const u32* __restrict__ counts,
    const float* __restrict__ vsum,
    const float* __restrict__ a0, const float* __restrict__ c0,
    const float* __restrict__ a1, const float* __restrict__ c1,
    const float* __restrict__ W1, const float* __restrict__ W2,
    float* __restrict__ sum2, float* __restrict__ sq2){
  __shared__ u32 rows[256*32];
  __shared__ float ws[4][64], wq[4][64];
  int t = threadIdx.x, sw = t&31;
  int p = blockIdx.x*256 + t;
  u32 v;
  chain_y1_row(p, sw, &rows[t*32], pts, lin, counts, vsum, a0,c0,a1,c1, W1, &v);
  int lane = t&63, wv = t>>6;
  for(int h=0; h<2; h++){
    float acc[64];
    #pragma unroll
    for(int j=0;j<64;j++) acc[j]=0.f;
    row_gemm64(&rows[t*32], sw, 32, W2, 128, h*64, acc);
    float ks=0.f, kq=0.f;
    #pragma unroll
    for(int c=0;c<64;c++){
      float s=acc[c], q=acc[c]*acc[c];
      #pragma unroll
      for(int d=1; d<64; d<<=1){ s+=__shfl_xor(s,d); q+=__shfl_xor(q,d); }
      if(lane==c){ ks=s; kq=q; }
    }
    ws[wv][lane]=ks; wq[wv][lane]=kq;
    __syncthreads();
    if(t<64){
      float S=ws[0][t]+ws[1][t]+ws[2][t]+ws[3][t];
      float Q=wq[0][t]+wq[1][t]+wq[2][t]+wq[3][t];
      atomicAdd(&sum2[h*64+t],S); atomicAdd(&sq2[h*64+t],Q);
    }
    __syncthreads();
  }
}

// ---------------- stats3: channel sums of z3 (recomputed) ----------------
__global__ __launch_bounds__(256,1) void k_stats3(const float* __restrict__ pts,
    const u32* __restrict__ lin, const u32* __restrict__ counts,
    const float* __restrict__ vsum,
    const float* __restrict__ a0, const float* __restrict__ c0,
    const float* __restrict__ a1, const float* __restrict__ c1,
    const float* __restrict__ a2, const float* __restrict__ c2,
    const float* __restrict__ W1, const float* __restrict__ W2,
    const float* __restrict__ W3,
    float* __restrict__ sum3, float* __restrict__ sq3){
  __shared__ u32 rows[256*64];
  __shared__ float ws[4][64], wq[4][64];
  int t = threadIdx.x, sw = t&31;
  int p = blockIdx.x*256 + t;
  u32 v;
  chain_to_y2_row(p, sw, &rows[t*64], pts, lin, counts, vsum,
                  a0,c0,a1,c1,a2,c2, W1,W2, &v);
  int lane = t&63, wv = t>>6;
  for(int cc=0; cc<4; cc++){
    float acc[64];
    #pragma unroll
    for(int j=0;j<64;j++) acc[j]=0.f;
    row_gemm64(&rows[t*64], sw, 64, W3, 256, cc*64, acc);
    float ks=0.f, kq=0.f;
    #pragma unroll
    for(int c=0;c<64;c++){
      float s=acc[c], q=acc[c]*acc[c];
      #pragma unroll
      for(int d=1; d<64; d<<=1){ s+=__shfl_xor(s,d); q+=__shfl_xor(q,d); }
      if(lane==c){ ks=s; kq=q; }
    }
    ws[wv][lane]=ks; wq[wv][lane]=kq;
    __syncthreads();
    if(t<64){
      float S=ws[0][t]+ws[1][t]+ws[2][t]+ws[3][t];
      float Q=wq[0][t]+wq[1][t]+wq[2][t]+wq[3][t];
      atomicAdd(&sum3[cc*64+t],S); atomicAdd(&sq3[cc*64+t],Q);
    }
    __syncthreads();
  }
}

// ---------------- mega: chain->z4, segment-max (LDS atomic), voxel GEMM ------
__global__ __launch_bounds__(256,1) void k_mega(
    const float* __restrict__ pts, const u32* __restrict__ lin,
    const u32* __restrict__ counts, const float* __restrict__ vsum,
    const u32* __restrict__ offsets, const u32* __restrict__ order,
    const float* __restrict__ a0, const float* __restrict__ c0,
    const float* __restrict__ a1, const float* __restrict__ c1,
    const float* __restrict__ a2, const float* __restrict__ c2,
    const float* __restrict__ a3, const float* __restrict__ c3,
    const float* __restrict__ W1, const float* __restrict__ W2,
    const float* __restrict__ W3, const float* __restrict__ W4,
    const float* __restrict__ b4, const float* __restrict__ Wc,
    const float* __restrict__ bc, u16* __restrict__ comp){
  __shared__ u32 y2s[256*64];     // per-thread bf16-packed activation row, swizzled
  __shared__ u32 vmax[64*256];    // 64 voxels x 256 ch, monotone-u32 max keys
  int t = threadIdx.x;
  u32 v0 = (u32)blockIdx.x * 64u;
  for(int i=t; i<64*256; i+=256) vmax[i] = 0u;
  u32 lo = offsets[v0], hi = offsets[v0+64];
  __syncthreads();
  int sw = t & 31;
  u32* myrow = &y2s[t*64];

  for(u32 base=lo; base<hi; base+=256u){
    u32 pos = base + (u32)t;
    if(pos < hi){
      u32 p = order[pos], v;
      chain_to_y2_row((int)p, sw, myrow, pts, lin, counts, vsum,
                      a0,c0,a1,c1,a2,c2, W1,W2, &v);
      int wl = (int)(v - v0);
      int m = wl & 31;
      #pragma unroll 1
      for(int h=0; h<2; h++){
        float acc[128];
        #pragma unroll
        for(int j=0;j<128;j++) acc[j]=0.f;
        #pragma unroll 1
        for(int kc=0; kc<4; kc++){
          float z3c[64];
          #pragma unroll
          for(int j=0;j<64;j++) z3c[j]=0.f;
          row_gemm64(myrow, sw, 64, W3, 256, kc*64, z3c);
          #pragma unroll
          for(int k=0;k<64;k++)
            z3c[k] = fmaxf(a3[kc*64+k]*z3c[k] + c3[kc*64+k], 0.f);
          #pragma unroll
          for(int k=0;k<64;k++){
            float yk = z3c[k];
            const float* w4r = W4 + ((size_t)(kc*64+k))*256 + h*128;
            #pragma unroll
            for(int j=0;j<128;j++) acc[j] += yk * w4r[j];
          }
        }
        #pragma unroll
        for(int j=0;j<128;j++){
          int cch = h*128 + j;           // low 5 bits of cch are j&31
          atomicMax(&vmax[wl*256 + (cch ^ m)], fkey(acc[j]));
        }
      }
    }
  }
  __syncthreads();

  // comp = relu(voxmax(+b4) @ Wc + bc) * nonempty, bf16
  {
    int w = t & 63, g = t >> 6;
    u32 vg = v0 + (u32)w;
    bool nz = offsets[vg+1] > offsets[vg];
    int m = w & 31;
    float acc[16];
    #pragma unroll
    for(int i=0;i<16;i++) acc[i]=0.f;
    for(int k=0;k<256;k++){
      float xv = nz ? (fdec(vmax[w*256 + (k ^ m)]) + b4[k]) : 0.0f;
      const float* wcr = Wc + (size_t)k*64 + g*16;
      #pragma unroll
      for(int i=0;i<16;i++) acc[i] += xv * wcr[i];
    }
    u32 pk[8];
    #pragma unroll
    for(int i=0;i<8;i++){
      float v0f = nz ? fmaxf(acc[2*i]   + bc[g*16+2*i],   0.f) : 0.f;
      float v1f = nz ? fmaxf(acc[2*i+1] + bc[g*16+2*i+1], 0.f) : 0.f;
      pk[i] = (u32)f2bf(v0f) | ((u32)f2bf(v1f)<<16);
    }
    uint4* dst = (uint4*)(comp + (size_t)vg*64 + (size_t)g*16);
    dst[0] = make_uint4(pk[0],pk[1],pk[2],pk[3]);
    dst[1] = make_uint4(pk[4],pk[5],pk[6],pk[7]);
  }
}

// ---------------- residual image from comp ----------------
__global__ __launch_bounds__(256) void k_resid(const u16* __restrict__ comp,
                                               float* __restrict__ out){
  __shared__ u32 cl[4*128*32];    // [fr][128 vox][32 words], swizzled
  int t = threadIdx.x;
  int blk = blockIdx.x;
  int wq = blk & 3, h = (blk>>2) & 63, b = blk>>8;
  int w0 = wq*128;
  for(int fr=0; fr<4; fr++){
    const u32* src = (const u32*)comp + ((size_t)(((b*4+fr)*64 + h)*512 + w0))*32;
    for(int i=t; i<4096; i+=256){
      int vox = i>>5, wd = i&31;
      cl[fr*4096 + vox*32 + (wd ^ (vox&31))] = src[i];
    }
  }
  __syncthreads();
  int wl = t & 127, half = t >> 7;
  int mv = wl & 31;
  for(int ch = half; ch < 64; ch += 2){
    u32 wr3 = cl[3*4096 + wl*32 + ((ch>>1) ^ mv)];
    float r3 = bf2f((ch&1) ? (u16)(wr3>>16) : (u16)(wr3&0xFFFFu));
    #pragma unroll
    for(int fr=0; fr<3; fr++){
      u32 wrf = cl[fr*4096 + wl*32 + ((ch>>1) ^ mv)];
      float vf = bf2f((ch&1) ? (u16)(wrf>>16) : (u16)(wrf&0xFFFFu));
      out[(((size_t)(b*192 + fr*64 + ch))*64 + h)*512 + w0 + wl] = r3 - vf;
    }
  }
}

// ------------------------------- launcher -------------------------------------
extern "C" void kernel_launch(void* const* d_in, const int* in_sizes, int n_in,
                              void* d_out, int out_size, void* d_ws, size_t ws_size,
                              hipStream_t stream){
  const float* pts  = (const float*)d_in[0];
  const int*  coors = (const int*)d_in[1];
  const float* g0 = (const float*)d_in[2];
  const float* b0 = (const float*)d_in[3];
  const float* W1 = (const float*)d_in[4];
  const float* g1 = (const float*)d_in[5];
  const float* b1 = (const float*)d_in[6];
  const float* W2 = (const float*)d_in[7];
  const float* g2 = (const float*)d_in[8];
  const float* b2 = (const float*)d_in[9];
  const float* W3 = (const float*)d_in[10];
  const float* g3 = (const float*)d_in[11];
  const float* b3 = (const float*)d_in[12];
  const float* W4 = (const float*)d_in[13];
  const float* b4 = (const float*)d_in[14];
  const float* Wc = (const float*)d_in[15];
  const float* bc = (const float*)d_in[16];
  float* out = (float*)d_out;
  (void)in_sizes; (void)n_in; (void)out_size; (void)ws_size;

  char* ws = (char*)d_ws;
  size_t off = 0;
  auto alloc = [&](size_t bytes)->void*{
    void* p = ws + off;
    off += (bytes + 255) & ~(size_t)255;
    return p;
  };
  u32*  counts  = (u32*)alloc((size_t)SS*4);        // 1 MiB
  float* vsum   = (float*)alloc((size_t)SS*3*4);    // 3 MiB
  float* stats  = (float*)alloc(8192);
  size_t zero_bytes = off;                          // counts + vsum + stats
  u32*  lin     = (u32*)alloc((size_t)NPTS*4);      // 2 MiB
  u32*  offsets = (u32*)alloc((size_t)(SS+1)*4);
  u32*  cursor  = (u32*)alloc((size_t)SS*4);
  u32*  order   = (u32*)alloc((size_t)NPTS*4);      // 2 MiB
  u32*  blockSums = (u32*)alloc(1024);
  u16*  comp    = (u16*)alloc((size_t)SS*64*2);     // 32 MiB
  // total ~45 MiB

  float* sum0=stats+0,   *sq0=stats+8,    *a0=stats+16,   *c0=stats+24;
  float* sum1=stats+32,  *sq1=stats+96,   *a1=stats+160,  *c1=stats+224;
  float* sum2=stats+288, *sq2=stats+416,  *a2=stats+544,  *c2=stats+672;
  float* sum3=stats+800, *sq3=stats+1056, *a3=stats+1312, *c3=stats+1568;

  hipMemsetAsync(d_ws, 0, zero_bytes, stream);

  k_lin    <<<2048,256,0,stream>>>(pts, coors, lin, counts, vsum);
  k_scan_a <<<256, 256,0,stream>>>(counts, blockSums);
  k_scan_b <<<1,   64, 0,stream>>>(blockSums);
  k_scan_c <<<256, 256,0,stream>>>(counts, blockSums, offsets, cursor);
  k_scatter<<<2048,256,0,stream>>>(lin, cursor, order);

  k_stats0 <<<2048,256,0,stream>>>(pts, lin, counts, vsum, sum0, sq0);
  k_fold   <<<1,   64, 0,stream>>>(sum0, sq0, g0, b0, a0, c0, 8);
  k_stats1 <<<2048,256,0,stream>>>(pts, lin, counts, vsum, a0, c0, W1, sum1, sq1);
  k_fold   <<<1,   64, 0,stream>>>(sum1, sq1, g1, b1, a1, c1, 64);
  k_stats2 <<<2048,256,0,stream>>>(pts, lin, counts, vsum, a0,c0,a1,c1, W1,W2, sum2, sq2);
  k_fold   <<<2,   64, 0,stream>>>(sum2, sq2, g2, b2, a2, c2, 128);
  k_stats3 <<<2048,256,0,stream>>>(pts, lin, counts, vsum, a0,c0,a1,c1,a2,c2, W1,W2,W3, sum3, sq3);
  k_fold   <<<4,   64, 0,stream>>>(sum3, sq3, g3, b3, a3, c3, 256);

  k_mega   <<<4096,256,0,stream>>>(pts, lin, counts, vsum, offsets, order,
                                   a0,c0,a1,c1,a2,c2,a3,c3,
                                   W1,W2,W3,W4,b4,Wc,bc, comp);
  k_resid  <<<512, 256,0,stream>>>(comp, out);
}

// Round 3
// 3225.032 us; speedup vs baseline: 4.0629x; 4.0629x over previous
//
#include <hip/hip_runtime.h>
#include <hip/hip_bf16.h>
#include <stdint.h>

typedef unsigned int u32;
typedef unsigned short u16;
typedef __attribute__((ext_vector_type(8))) short bf16x8;
typedef __attribute__((ext_vector_type(4))) float f32x4;

#define NPTS 524288
#define FF 4
#define HH 64
#define WW 512
#define SS 262144
#define EPSV 1e-5f
#define NB 4096
#define RCAP 144
#define VCAP 96

__device__ __forceinline__ float bf2f(u16 h){ return __uint_as_float(((u32)h)<<16); }
__device__ __forceinline__ u16 f2bf(float f){
  u32 u = __float_as_uint(f);
  return (u16)((u + 0x7FFFu + ((u>>16)&1u)) >> 16);   // RNE
}
// monotone f32 <-> u32 key for atomicMax-based float max
__device__ __forceinline__ u32 fkey(float f){
  u32 u = __float_as_uint(f);
  return u ^ ((u32)(((int)u) >> 31) | 0x80000000u);
}
__device__ __forceinline__ float fdec(u32 k){
  u32 u = (k & 0x80000000u) ? (k ^ 0x80000000u) : ~k;
  return __uint_as_float(u);
}

// ---------------- shared chain pieces (stats path) ----------------
__device__ __forceinline__ void point_feats(int p, const float* __restrict__ pts,
    const u32* __restrict__ lin, const u32* __restrict__ counts,
    const float* __restrict__ vsum, float f[8], u32* vout){
  float4 pt = ((const float4*)pts)[p];
  u32 v = lin[p];
  float cnt = fmaxf((float)counts[v], 1.0f);
  float inv = 1.0f/cnt;
  float mx = vsum[v*3+0]*inv, my = vsum[v*3+1]*inv, mz = vsum[v*3+2]*inv;
  float dist = sqrtf(pt.x*pt.x + pt.y*pt.y + pt.z*pt.z);
  f[0]=pt.x; f[1]=pt.y; f[2]=pt.z; f[3]=pt.w; f[4]=dist;
  f[5]=pt.x-mx; f[6]=pt.y-my; f[7]=pt.z-mz;
  *vout = v;
}

__device__ __forceinline__ void row_gemm64(const u32* row, int sw, int kPairs,
    const float* __restrict__ W, int ldw, int jbase, float acc[64]){
  for(int kk=0; kk<kPairs; ++kk){
    u32 pr = row[kk ^ sw];
    float e0 = bf2f((u16)(pr & 0xFFFFu));
    float e1 = bf2f((u16)(pr >> 16));
    const float* w0 = W + (size_t)(2*kk)*ldw + jbase;
    const float* w1 = w0 + ldw;
    #pragma unroll
    for(int j=0;j<64;j++) acc[j] += e0*w0[j] + e1*w1[j];
  }
}

__device__ __forceinline__ void chain_y1_row(int p, int sw, u32* row,
    const float* __restrict__ pts, const u32* __restrict__ lin,
    const u32* __restrict__ counts, const float* __restrict__ vsum,
    const float* __restrict__ a0, const float* __restrict__ c0,
    const float* __restrict__ a1, const float* __restrict__ c1,
    const float* __restrict__ W1, u32* vout){
  float f[8]; point_feats(p, pts, lin, counts, vsum, f, vout);
  float y0[8];
  #pragma unroll
  for(int k=0;k<8;k++) y0[k] = a0[k]*f[k] + c0[k];
  #pragma unroll
  for(int jj=0;jj<32;jj++){
    float s0=0.f, s1=0.f;
    #pragma unroll
    for(int k=0;k<8;k++){ s0 += y0[k]*W1[k*64+2*jj]; s1 += y0[k]*W1[k*64+2*jj+1]; }
    float v0f = fmaxf(a1[2*jj]*s0   + c1[2*jj],   0.f);
    float v1f = fmaxf(a1[2*jj+1]*s1 + c1[2*jj+1], 0.f);
    row[jj ^ sw] = (u32)f2bf(v0f) | ((u32)f2bf(v1f)<<16);
  }
}

__device__ __forceinline__ void chain_to_y2_row(int p, int sw, u32* row,
    const float* __restrict__ pts, const u32* __restrict__ lin,
    const u32* __restrict__ counts, const float* __restrict__ vsum,
    const float* __restrict__ a0, const float* __restrict__ c0,
    const float* __restrict__ a1, const float* __restrict__ c1,
    const float* __restrict__ a2, const float* __restrict__ c2,
    const float* __restrict__ W1, const float* __restrict__ W2, u32* vout){
  chain_y1_row(p, sw, row, pts, lin, counts, vsum, a0, c0, a1, c1, W1, vout);
  float y2[128];
  #pragma unroll
  for(int h=0;h<2;h++){
    float acc[64];
    #pragma unroll
    for(int j=0;j<64;j++) acc[j]=0.f;
    row_gemm64(row, sw, 32, W2, 128, h*64, acc);
    #pragma unroll
    for(int j=0;j<64;j++) y2[h*64+j] = fmaxf(a2[h*64+j]*acc[j] + c2[h*64+j], 0.f);
  }
  #pragma unroll
  for(int jj=0;jj<64;jj++)
    row[jj ^ sw] = (u32)f2bf(y2[2*jj]) | ((u32)f2bf(y2[2*jj+1])<<16);
}

// ---------------- pass 1: linear voxel id + counts + coord sums ----------------
__global__ __launch_bounds__(256) void k_lin(const float* __restrict__ pts,
                                             const int* __restrict__ coors,
                                             u32* __restrict__ lin,
                                             u32* __restrict__ counts,
                                             float* __restrict__ vsum){
  int p = blockIdx.x*256 + threadIdx.x;
  int4 c = ((const int4*)coors)[p];
  u32 v = ((u32)((c.x*FF + c.y)*HH + c.z))*WW + (u32)c.w;
  lin[p] = v;
  atomicAdd(&counts[v], 1u);
  float4 pt = ((const float4*)pts)[p];
  atomicAdd(&vsum[v*3+0], pt.x);
  atomicAdd(&vsum[v*3+1], pt.y);
  atomicAdd(&vsum[v*3+2], pt.z);
}

// ---------------- counting-sort scan ----------------
__global__ __launch_bounds__(256) void k_scan_a(const u32* __restrict__ counts,
                                                u32* __restrict__ blockSums){
  __shared__ u32 lds[256];
  int b = blockIdx.x, t = threadIdx.x;
  uint4 c4 = ((const uint4*)counts)[b*256 + t];
  lds[t] = c4.x + c4.y + c4.z + c4.w;
  __syncthreads();
  for(int s=128; s>0; s>>=1){ if(t<s) lds[t] += lds[t+s]; __syncthreads(); }
  if(t==0) blockSums[b] = lds[0];
}

__global__ void k_scan_b(u32* blockSums){
  if(threadIdx.x==0){
    u32 run = 0;
    for(int i=0;i<256;i++){ u32 v = blockSums[i]; blockSums[i] = run; run += v; }
  }
}

__global__ __launch_bounds__(256) void k_scan_c(const u32* __restrict__ counts,
                                                const u32* __restrict__ blockSums,
                                                u32* __restrict__ offsets,
                                                u32* __restrict__ cursor){
  __shared__ u32 lds[256];
  int b = blockIdx.x, t = threadIdx.x;
  uint4 c4 = ((const uint4*)counts)[b*256 + t];
  u32 mysum = c4.x + c4.y + c4.z + c4.w;
  lds[t] = mysum;
  __syncthreads();
  for(int d=1; d<256; d<<=1){
    u32 v = (t>=d) ? lds[t-d] : 0u;
    __syncthreads();
    lds[t] += v;
    __syncthreads();
  }
  u32 off = blockSums[b] + (t>0 ? lds[t-1] : 0u);
  u32 base = (u32)(b*1024 + t*4);
  offsets[base+0]=off; cursor[base+0]=off; off += c4.x;
  offsets[base+1]=off; cursor[base+1]=off; off += c4.y;
  offsets[base+2]=off; cursor[base+2]=off; off += c4.z;
  offsets[base+3]=off; cursor[base+3]=off; off += c4.w;
  if(base+4 == SS) offsets[SS] = off;
}

__global__ __launch_bounds__(256) void k_scatter(const u32* __restrict__ lin,
                                                 u32* __restrict__ cursor,
                                                 u32* __restrict__ order){
  int p = blockIdx.x*256 + threadIdx.x;
  u32 v = lin[p];
  u32 pos = atomicAdd(&cursor[v], 1u);
  order[pos] = p;
}

// ---------------- weight prep: bf16 transposed + bf16-rounded f32 ----------------
__global__ __launch_bounds__(256) void k_prep(const float* __restrict__ W2,
    const float* __restrict__ W3, const float* __restrict__ W4,
    const float* __restrict__ Wc,
    u16* __restrict__ W2t, u16* __restrict__ W3t, u16* __restrict__ W4t,
    u16* __restrict__ Wct, float* __restrict__ W2r, float* __restrict__ W3r){
  int i = blockIdx.x*256 + threadIdx.x;
  if(i < 8192){
    int k = i >> 7, n = i & 127;
    u16 b = f2bf(W2[i]);
    W2t[n*64 + k] = b; W2r[i] = bf2f(b);
  } else if(i < 8192+32768){
    int j = i - 8192;
    int k = j >> 8, n = j & 255;
    u16 b = f2bf(W3[j]);
    W3t[n*128 + k] = b; W3r[j] = bf2f(b);
  } else if(i < 8192+32768+65536){
    int j = i - (8192+32768);
    int k = j >> 8, n = j & 255;
    W4t[n*256 + k] = f2bf(W4[j]);
  } else if(i < 8192+32768+65536+16384){
    int j = i - (8192+32768+65536);
    int k = j >> 6, n = j & 63;
    Wct[n*256 + k] = f2bf(Wc[j]);
  }
}

// ---------------- stats0 ----------------
__global__ __launch_bounds__(256) void k_stats0(const float* __restrict__ pts,
    const u32* __restrict__ lin, const u32* __restrict__ counts,
    const float* __restrict__ vsum, float* __restrict__ sum0, float* __restrict__ sq0){
  int p = blockIdx.x*256 + threadIdx.x;
  float f[8]; u32 v;
  point_feats(p, pts, lin, counts, vsum, f, &v);
  __shared__ float lsum[4][8], lsq[4][8];
  int lane = threadIdx.x & 63, wv = threadIdx.x >> 6;
  #pragma unroll
  for(int c=0;c<8;c++){
    float s = f[c], q = f[c]*f[c];
    #pragma unroll
    for(int d=32; d; d>>=1){ s += __shfl_xor(s,d); q += __shfl_xor(q,d); }
    if(lane==0){ lsum[wv][c]=s; lsq[wv][c]=q; }
  }
  __syncthreads();
  if(threadIdx.x<8){
    float s=0.f,q=0.f;
    for(int g=0;g<4;g++){ s+=lsum[g][threadIdx.x]; q+=lsq[g][threadIdx.x]; }
    atomicAdd(&sum0[threadIdx.x], s);
    atomicAdd(&sq0[threadIdx.x], q);
  }
}

// ---------------- fold BN stats -> (a,c) ----------------
__global__ void k_fold(const float* __restrict__ sum, const float* __restrict__ sq,
                       const float* __restrict__ g, const float* __restrict__ b,
                       float* __restrict__ a, float* __restrict__ c, int C){
  int i = blockIdx.x*64 + threadIdx.x;
  if(i < C){
    float m = sum[i]*(1.0f/NPTS);
    float v = sq[i]*(1.0f/NPTS) - m*m;
    v = fmaxf(v, 0.0f);
    float ai = g[i] / sqrtf(v + EPSV);
    a[i] = ai;
    c[i] = b[i] - m*ai;
  }
}

// ---------------- stats1 ----------------
__global__ __launch_bounds__(256) void k_stats1(const float* __restrict__ pts,
    const u32* __restrict__ lin, const u32* __restrict__ counts,
    const float* __restrict__ vsum,
    const float* __restrict__ a0, const float* __restrict__ c0,
    const float* __restrict__ W1, float* __restrict__ sum1, float* __restrict__ sq1){
  __shared__ float ws[4][64], wq[4][64];
  int t = threadIdx.x;
  int p = blockIdx.x*256 + t;
  float f[8]; u32 v;
  point_feats(p, pts, lin, counts, vsum, f, &v);
  float y0[8];
  #pragma unroll
  for(int k=0;k<8;k++) y0[k] = a0[k]*f[k] + c0[k];
  float z[64];
  #pragma unroll
  for(int j=0;j<64;j++){
    float s=0.f;
    #pragma unroll
    for(int k=0;k<8;k++) s += y0[k]*W1[k*64+j];
    z[j]=s;
  }
  int lane = t&63, wv = t>>6;
  float ks=0.f, kq=0.f;
  #pragma unroll
  for(int c=0;c<64;c++){
    float s=z[c], q=z[c]*z[c];
    #pragma unroll
    for(int d=1; d<64; d<<=1){ s+=__shfl_xor(s,d); q+=__shfl_xor(q,d); }
    if(lane==c){ ks=s; kq=q; }
  }
  ws[wv][lane]=ks; wq[wv][lane]=kq;
  __syncthreads();
  if(t<64){
    float S=ws[0][t]+ws[1][t]+ws[2][t]+ws[3][t];
    float Q=wq[0][t]+wq[1][t]+wq[2][t]+wq[3][t];
    atomicAdd(&sum1[t],S); atomicAdd(&sq1[t],Q);
  }
}

// ---------------- stats2 ----------------
__global__ __launch_bounds__(256) void k_stats2(const float* __restrict__ pts,
    const u32* __restrict__ lin, const u32* __restrict__ counts,
    const float* __restrict__ vsum,
    const float* __restrict__ a0, const float* __restrict__ c0,
    const float* __restrict__ a1, const float* __restrict__ c1,
    const float* __restrict__ W1, const float* __restrict__ W2,
    float* __restrict__ sum2, float* __restrict__ sq2){
  __shared__ u32 rows[256*32];
  __shared__ float ws[4][64], wq[4][64];
  int t = threadIdx.x, sw = t&31;
  int p = blockIdx.x*256 + t;
  u32 v;
  chain_y1_row(p, sw, &rows[t*32], pts, lin, counts, vsum, a0,c0,a1,c1, W1, &v);
  int lane = t&63, wv = t>>6;
  for(int h=0; h<2; h++){
    float acc[64];
    #pragma unroll
    for(int j=0;j<64;j++) acc[j]=0.f;
    row_gemm64(&rows[t*32], sw, 32, W2, 128, h*64, acc);
    float ks=0.f, kq=0.f;
    #pragma unroll
    for(int c=0;c<64;c++){
      float s=acc[c], q=acc[c]*acc[c];
      #pragma unroll
      for(int d=1; d<64; d<<=1){ s+=__shfl_xor(s,d); q+=__shfl_xor(q,d); }
      if(lane==c){ ks=s; kq=q; }
    }
    ws[wv][lane]=ks; wq[wv][lane]=kq;
    __syncthreads();
    if(t<64){
      float S=ws[0][t]+ws[1][t]+ws[2][t]+ws[3][t];
      float Q=wq[0][t]+wq[1][t]+wq[2][t]+wq[3][t];
      atomicAdd(&sum2[h*64+t],S); atomicAdd(&sq2[h*64+t],Q);
    }
    __syncthreads();
  }
}

// ---------------- stats3 ----------------
__global__ __launch_bounds__(256,1) void k_stats3(const float* __restrict__ pts,
    const u32* __restrict__ lin, const u32* __restrict__ counts,
    const float* __restrict__ vsum,
    const float* __restrict__ a0, const float* __restrict__ c0,
    const float* __restrict__ a1, const float* __restrict__ c1,
    const float* __restrict__ a2, const float* __restrict__ c2,
    const float* __restrict__ W1, const float* __restrict__ W2,
    const float* __restrict__ W3,
    float* __restrict__ sum3, float* __restrict__ sq3){
  __shared__ u32 rows[256*64];
  __shared__ float ws[4][64], wq[4][64];
  int t = threadIdx.x, sw = t&31;
  int p = blockIdx.x*256 + t;
  u32 v;
  chain_to_y2_row(p, sw, &rows[t*64], pts, lin, counts, vsum,
                  a0,c0,a1,c1,a2,c2, W1,W2, &v);
  int lane = t&63, wv = t>>6;
  for(int cc=0; cc<4; cc++){
    float acc[64];
    #pragma unroll
    for(int j=0;j<64;j++) acc[j]=0.f;
    row_gemm64(&rows[t*64], sw, 64, W3, 256, cc*64, acc);
    float ks=0.f, kq=0.f;
    #pragma unroll
    for(int c=0;c<64;c++){
      float s=acc[c], q=acc[c]*acc[c];
      #pragma unroll
      for(int d=1; d<64; d<<=1){ s+=__shfl_xor(s,d); q+=__shfl_xor(q,d); }
      if(lane==c){ ks=s; kq=q; }
    }
    ws[wv][lane]=ks; wq[wv][lane]=kq;
    __syncthreads();
    if(t<64){
      float S=ws[0][t]+ws[1][t]+ws[2][t]+ws[3][t];
      float Q=wq[0][t]+wq[1][t]+wq[2][t]+wq[3][t];
      atomicAdd(&sum3[cc*64+t],S); atomicAdd(&sq3[cc*64+t],Q);
    }
    __syncthreads();
  }
}

// ---------------- mega2: MFMA chain + segmax + voxel GEMM ----------------
__global__ __launch_bounds__(256,1) void k_mega2(
    const float* __restrict__ pts, const u32* __restrict__ lin,
    const u32* __restrict__ counts, const float* __restrict__ vsum,
    const u32* __restrict__ offsets, const u32* __restrict__ order,
    const float* __restrict__ a0, const float* __restrict__ c0,
    const float* __restrict__ a1, const float* __restrict__ c1,
    const float* __restrict__ a2, const float* __restrict__ c2,
    const float* __restrict__ a3, const float* __restrict__ c3,
    const float* __restrict__ W1,
    const u16* __restrict__ W2t, const u16* __restrict__ W3t,
    const u16* __restrict__ W4t, const u16* __restrict__ Wct,
    const float* __restrict__ b4, const float* __restrict__ bc,
    u16* __restrict__ comp){
  // LDS unions: X = T1(20736) / T3(76032); Y = T2(39168) / {vmax 25344 + TA 13824}
  __shared__ __align__(16) char SM[115712];
  u16* T1   = (u16*)(SM);                 // [144][72]
  u16* T3   = (u16*)(SM);                 // [144][264]
  u16* T2   = (u16*)(SM + 76032);         // [144][136]
  u32* vmax = (u32*)(SM + 76032);         // [96][66]
  u16* TA   = (u16*)(SM + 76032 + 25344); // [96][72]
  u16* rowvox = (u16*)(SM + 115200);      // [144]
  u16* nzf  = (u16*)(SM + 115200 + 288);  // [96]
  u32* hdr  = (u32*)(SM + 115200 + 480);  // [4]

  int tid = threadIdx.x, lane = tid & 63, wid = tid >> 6;
  int l15 = lane & 15, lg = lane >> 4;

  if(tid == 0){
    u32 t0 = (u32)blockIdx.x * 128u;
    u32 lo=0, hi=SS;
    while(lo<hi){ u32 mid=(lo+hi)>>1; if(offsets[mid] < t0) lo=mid+1; else hi=mid; }
    u32 vlo = lo, vhi;
    if(blockIdx.x == NB-1) vhi = SS;
    else {
      u32 t1 = t0 + 128u;
      lo = vlo; hi = SS;
      while(lo<hi){ u32 mid=(lo+hi)>>1; if(offsets[mid] < t1) lo=mid+1; else hi=mid; }
      vhi = lo;
    }
    hdr[0]=vlo; hdr[1]=vhi; hdr[2]=offsets[vlo]; hdr[3]=offsets[vhi];
  }
  __syncthreads();
  u32 vlo=hdr[0], vhi=hdr[1], start=hdr[2], end=hdr[3];
  int R = (int)(end - start); if(R > RCAP) R = RCAP;
  int V = (int)(vhi - vlo);   if(V > VCAP) V = VCAP;

  for(int v=tid; v<VCAP; v+=256)
    nzf[v] = (v < V && offsets[vlo+v+1] > offsets[vlo+v]) ? 1 : 0;

  // ---- feats + L1 scalar -> T1 (bf16 [144][72]) ----
  for(int r=tid; r<RCAP; r+=256){
    uint4* dst = (uint4*)&T1[r*72];
    if(r < R){
      u32 p = order[start + r];
      float4 pt = ((const float4*)pts)[p];
      u32 v = lin[p];
      float cnt = fmaxf((float)counts[v], 1.0f);
      float inv = 1.0f/cnt;
      float mx = vsum[v*3+0]*inv, my = vsum[v*3+1]*inv, mz = vsum[v*3+2]*inv;
      float dist = sqrtf(pt.x*pt.x + pt.y*pt.y + pt.z*pt.z);
      u32 dv = v - vlo; if(dv > (u32)(VCAP-1)) dv = VCAP-1;
      rowvox[r] = (u16)dv;
      float y0[8] = {pt.x, pt.y, pt.z, pt.w, dist, pt.x-mx, pt.y-my, pt.z-mz};
      #pragma unroll
      for(int k=0;k<8;k++) y0[k] = a0[k]*y0[k] + c0[k];
      u32 pk[32];
      #pragma unroll
      for(int jj=0; jj<32; jj++){
        float s0=0.f, s1=0.f;
        #pragma unroll
        for(int k=0;k<8;k++){ s0 += y0[k]*W1[k*64+2*jj]; s1 += y0[k]*W1[k*64+2*jj+1]; }
        float v0f = fmaxf(a1[2*jj]*s0   + c1[2*jj],   0.f);
        float v1f = fmaxf(a1[2*jj+1]*s1 + c1[2*jj+1], 0.f);
        pk[jj] = (u32)f2bf(v0f) | ((u32)f2bf(v1f)<<16);
      }
      #pragma unroll
      for(int q=0;q<8;q++) dst[q] = make_uint4(pk[4*q],pk[4*q+1],pk[4*q+2],pk[4*q+3]);
    } else {
      uint4 z = make_uint4(0,0,0,0);
      #pragma unroll
      for(int q=0;q<8;q++) dst[q] = z;
    }
  }
  __syncthreads();

  // ---- L2: T1(144x64) @ W2t -> bn2relu -> T2(144x128) ----
  for(int ci=0; ci<2; ci++){
    int ct = wid + 4*ci;
    int ch = ct*16 + l15;
    const u16* wb = W2t + (size_t)ch*64 + lg*8;
    bf16x8 b0 = *(const bf16x8*)(wb);
    bf16x8 b1 = *(const bf16x8*)(wb + 32);
    float a2v = a2[ch], c2v = c2[ch];
    for(int rt=0; rt<9; rt++){
      const u16* ap = T1 + (rt*16 + l15)*72 + lg*8;
      bf16x8 af0 = *(const bf16x8*)(ap);
      bf16x8 af1 = *(const bf16x8*)(ap + 32);
      f32x4 acc = {0.f,0.f,0.f,0.f};
      acc = __builtin_amdgcn_mfma_f32_16x16x32_bf16(af0, b0, acc, 0,0,0);
      acc = __builtin_amdgcn_mfma_f32_16x16x32_bf16(af1, b1, acc, 0,0,0);
      int rbase = rt*16 + lg*4;
      #pragma unroll
      for(int i=0;i<4;i++)
        T2[(rbase+i)*136 + ch] = f2bf(fmaxf(a2v*acc[i] + c2v, 0.f));
    }
  }
  __syncthreads();

  // ---- L3: T2(144x128) @ W3t -> bn3relu -> T3(144x256) ----
  for(int ci=0; ci<4; ci++){
    int ct = wid + 4*ci;
    int ch = ct*16 + l15;
    const u16* wb = W3t + (size_t)ch*128 + lg*8;
    bf16x8 b[4];
    #pragma unroll
    for(int ks=0; ks<4; ks++) b[ks] = *(const bf16x8*)(wb + ks*32);
    float a3v = a3[ch], c3v = c3[ch];
    for(int rt=0; rt<9; rt++){
      const u16* ap = T2 + (rt*16 + l15)*136 + lg*8;
      f32x4 acc = {0.f,0.f,0.f,0.f};
      #pragma unroll
      for(int ks=0; ks<4; ks++){
        bf16x8 af = *(const bf16x8*)(ap + ks*32);
        acc = __builtin_amdgcn_mfma_f32_16x16x32_bf16(af, b[ks], acc, 0,0,0);
      }
      int rbase = rt*16 + lg*4;
      #pragma unroll
      for(int i=0;i<4;i++)
        T3[(rbase+i)*264 + ch] = f2bf(fmaxf(a3v*acc[i] + c3v, 0.f));
    }
  }
  __syncthreads();

  // ---- L4 (64-col chunks) + segmax + fused voxel GEMM accumulation ----
  f32x4 acc6[6];
  #pragma unroll
  for(int i=0;i<6;i++) acc6[i] = (f32x4){0.f,0.f,0.f,0.f};
  int ch4 = wid*16 + l15;   // column within 64-chunk / comp output channel

  for(int oc=0; oc<4; oc++){
    for(int i=tid; i<VCAP*66; i+=256) vmax[i] = 0u;
    __syncthreads();
    // z4 chunk: T3(144x256) @ W4t[:, oc*64 + wid*16 ...]
    {
      int chg = oc*64 + ch4;
      const u16* wb = W4t + (size_t)chg*256 + lg*8;
      bf16x8 b[8];
      #pragma unroll
      for(int ks=0; ks<8; ks++) b[ks] = *(const bf16x8*)(wb + ks*32);
      for(int rt=0; rt<9; rt++){
        const u16* ap = T3 + (rt*16 + l15)*264 + lg*8;
        f32x4 acc = {0.f,0.f,0.f,0.f};
        #pragma unroll
        for(int ks=0; ks<8; ks++){
          bf16x8 af = *(const bf16x8*)(ap + ks*32);
          acc = __builtin_amdgcn_mfma_f32_16x16x32_bf16(af, b[ks], acc, 0,0,0);
        }
        int rbase = rt*16 + lg*4;
        #pragma unroll
        for(int i=0;i<4;i++){
          int row = rbase + i;
          if(row < R)
            atomicMax(&vmax[(u32)rowvox[row]*66u + (u32)ch4], fkey(acc[i]));
        }
      }
    }
    __syncthreads();
    // TA = (vmax + b4) bf16, zero for empty voxels
    for(int i=tid; i<VCAP*64; i+=256){
      int v = i>>6, k = i&63;
      u16 val = 0;
      if(nzf[v]) val = f2bf(fdec(vmax[v*66+k]) + b4[oc*64+k]);
      TA[v*72+k] = val;
    }
    __syncthreads();
    // comp partial: TA(96 x 64) @ Wct[:, k-chunk]
    {
      const u16* wb = Wct + (size_t)ch4*256 + oc*64 + lg*8;
      bf16x8 b0 = *(const bf16x8*)(wb);
      bf16x8 b1 = *(const bf16x8*)(wb + 32);
      #pragma unroll
      for(int vt=0; vt<6; vt++){
        const u16* ap = TA + (vt*16 + l15)*72 + lg*8;
        bf16x8 af0 = *(const bf16x8*)(ap);
        bf16x8 af1 = *(const bf16x8*)(ap + 32);
        acc6[vt] = __builtin_amdgcn_mfma_f32_16x16x32_bf16(af0, b0, acc6[vt], 0,0,0);
        acc6[vt] = __builtin_amdgcn_mfma_f32_16x16x32_bf16(af1, b1, acc6[vt], 0,0,0);
      }
    }
    __syncthreads();
  }

  // ---- comp write ----
  {
    float bcv = bc[ch4];
    #pragma unroll
    for(int vt=0; vt<6; vt++){
      int vbase = vt*16 + lg*4;
      #pragma unroll
      for(int i=0;i<4;i++){
        int vox = vbase + i;
        if(vox < V){
          float val = nzf[vox] ? fmaxf(acc6[vt][i] + bcv, 0.f) : 0.f;
          comp[(size_t)(vlo+vox)*64 + ch4] = f2bf(val);
        }
      }
    }
  }
}

// ---------------- residual image from comp ----------------
__global__ __launch_bounds__(256) void k_resid(const u16* __restrict__ comp,
                                               float* __restrict__ out){
  __shared__ u32 cl[4*128*32];
  int t = threadIdx.x;
  int blk = blockIdx.x;
  int wq = blk & 3, h = (blk>>2) & 63, b = blk>>8;
  int w0 = wq*128;
  for(int fr=0; fr<4; fr++){
    const u32* src = (const u32*)comp + ((size_t)(((b*4+fr)*64 + h)*512 + w0))*32;
    for(int i=t; i<4096; i+=256){
      int vox = i>>5, wd = i&31;
      cl[fr*4096 + vox*32 + (wd ^ (vox&31))] = src[i];
    }
  }
  __syncthreads();
  int wl = t & 127, half = t >> 7;
  int mv = wl & 31;
  for(int ch = half; ch < 64; ch += 2){
    u32 wr3 = cl[3*4096 + wl*32 + ((ch>>1) ^ mv)];
    float r3 = bf2f((ch&1) ? (u16)(wr3>>16) : (u16)(wr3&0xFFFFu));
    #pragma unroll
    for(int fr=0; fr<3; fr++){
      u32 wrf = cl[fr*4096 + wl*32 + ((ch>>1) ^ mv)];
      float vf = bf2f((ch&1) ? (u16)(wrf>>16) : (u16)(wrf&0xFFFFu));
      out[(((size_t)(b*192 + fr*64 + ch))*64 + h)*512 + w0 + wl] = r3 - vf;
    }
  }
}

// ------------------------------- launcher -------------------------------------
extern "C" void kernel_launch(void* const* d_in, const int* in_sizes, int n_in,
                              void* d_out, int out_size, void* d_ws, size_t ws_size,
                              hipStream_t stream){
  const float* pts  = (const float*)d_in[0];
  const int*  coors = (const int*)d_in[1];
  const float* g0 = (const float*)d_in[2];
  const float* b0 = (const float*)d_in[3];
  const float* W1 = (const float*)d_in[4];
  const float* g1 = (const float*)d_in[5];
  const float* b1 = (const float*)d_in[6];
  const float* W2 = (const float*)d_in[7];
  const float* g2 = (const float*)d_in[8];
  const float* b2 = (const float*)d_in[9];
  const float* W3 = (const float*)d_in[10];
  const float* g3 = (const float*)d_in[11];
  const float* b3 = (const float*)d_in[12];
  const float* W4 = (const float*)d_in[13];
  const float* b4 = (const float*)d_in[14];
  const float* Wc = (const float*)d_in[15];
  const float* bc = (const float*)d_in[16];
  float* out = (float*)d_out;
  (void)in_sizes; (void)n_in; (void)out_size; (void)ws_size;

  char* ws = (char*)d_ws;
  size_t off = 0;
  auto alloc = [&](size_t bytes)->void*{
    void* p = ws + off;
    off += (bytes + 255) & ~(size_t)255;
    return p;
  };
  u32*  counts  = (u32*)alloc((size_t)SS*4);
  float* vsum   = (float*)alloc((size_t)SS*3*4);
  float* stats  = (float*)alloc(8192);
  size_t zero_bytes = off;
  u32*  lin     = (u32*)alloc((size_t)NPTS*4);
  u32*  offsets = (u32*)alloc((size_t)(SS+1)*4);
  u32*  cursor  = (u32*)alloc((size_t)SS*4);
  u32*  order   = (u32*)alloc((size_t)NPTS*4);
  u32*  blockSums = (u32*)alloc(1024);
  u16*  comp    = (u16*)alloc((size_t)SS*64*2);
  u16*  W2t = (u16*)alloc(8192*2);
  u16*  W3t = (u16*)alloc(32768*2);
  u16*  W4t = (u16*)alloc(65536*2);
  u16*  Wct = (u16*)alloc(16384*2);
  float* W2r = (float*)alloc(8192*4);
  float* W3r = (float*)alloc(32768*4);

  float* sum0=stats+0,   *sq0=stats+8,    *a0=stats+16,   *c0=stats+24;
  float* sum1=stats+32,  *sq1=stats+96,   *a1=stats+160,  *c1=stats+224;
  float* sum2=stats+288, *sq2=stats+416,  *a2=stats+544,  *c2=stats+672;
  float* sum3=stats+800, *sq3=stats+1056, *a3=stats+1312, *c3=stats+1568;

  hipMemsetAsync(d_ws, 0, zero_bytes, stream);

  k_prep   <<<480, 256,0,stream>>>(W2, W3, W4, Wc, W2t, W3t, W4t, Wct, W2r, W3r);
  k_lin    <<<2048,256,0,stream>>>(pts, coors, lin, counts, vsum);
  k_scan_a <<<256, 256,0,stream>>>(counts, blockSums);
  k_scan_b <<<1,   64, 0,stream>>>(blockSums);
  k_scan_c <<<256, 256,0,stream>>>(counts, blockSums, offsets, cursor);
  k_scatter<<<2048,256,0,stream>>>(lin, cursor, order);

  k_stats0 <<<2048,256,0,stream>>>(pts, lin, counts, vsum, sum0, sq0);
  k_fold   <<<1,   64, 0,stream>>>(sum0, sq0, g0, b0, a0, c0, 8);
  k_stats1 <<<2048,256,0,stream>>>(pts, lin, counts, vsum, a0, c0, W1, sum1, sq1);
  k_fold   <<<1,   64, 0,stream>>>(sum1, sq1, g1, b1, a1, c1, 64);
  k_stats2 <<<2048,256,0,stream>>>(pts, lin, counts, vsum, a0,c0,a1,c1, W1,W2r, sum2, sq2);
  k_fold   <<<2,   64, 0,stream>>>(sum2, sq2, g2, b2, a2, c2, 128);
  k_stats3 <<<2048,256,0,stream>>>(pts, lin, counts, vsum, a0,c0,a1,c1,a2,c2, W1,W2r,W3r, sum3, sq3);
  k_fold   <<<4,   64, 0,stream>>>(sum3, sq3, g3, b3, a3, c3, 256);

  k_mega2  <<<NB,  256,0,stream>>>(pts, lin, counts, vsum, offsets, order,
                                   a0,c0,a1,c1,a2,c2,a3,c3,
                                   W1, W2t, W3t, W4t, Wct, b4, bc, comp);
  k_resid  <<<512, 256,0,stream>>>(comp, out);
}

// Round 5
// 1433.014 us; speedup vs baseline: 9.1436x; 2.2505x over previous
//
#include <hip/hip_runtime.h>
#include <hip/hip_bf16.h>
#include <stdint.h>

typedef unsigned int u32;
typedef unsigned short u16;
typedef __attribute__((ext_vector_type(8))) short bf16x8;
typedef __attribute__((ext_vector_type(4))) float f32x4;

#define NPTS 524288
#define FF 4
#define HH 64
#define WW 512
#define SS 262144
#define EPSV 1e-5f
#define NB 4096
#define RCAP 144
#define VCAP 96

__device__ __forceinline__ float bf2f(u16 h){ return __uint_as_float(((u32)h)<<16); }
__device__ __forceinline__ u16 f2bf(float f){
  u32 u = __float_as_uint(f);
  return (u16)((u + 0x7FFFu + ((u>>16)&1u)) >> 16);   // RNE
}
// monotone f32 <-> u32 key for atomicMax-based float max
__device__ __forceinline__ u32 fkey(float f){
  u32 u = __float_as_uint(f);
  return u ^ ((u32)(((int)u) >> 31) | 0x80000000u);
}
__device__ __forceinline__ float fdec(u32 k){
  u32 u = (k & 0x80000000u) ? (k ^ 0x80000000u) : ~k;
  return __uint_as_float(u);
}

__device__ __forceinline__ void point_feats(int p, const float* __restrict__ pts,
    const u32* __restrict__ lin, const u32* __restrict__ counts,
    const float* __restrict__ vsum, float f[8], u32* vout){
  float4 pt = ((const float4*)pts)[p];
  u32 v = lin[p];
  float cnt = fmaxf((float)counts[v], 1.0f);
  float inv = 1.0f/cnt;
  float mx = vsum[v*3+0]*inv, my = vsum[v*3+1]*inv, mz = vsum[v*3+2]*inv;
  float dist = sqrtf(pt.x*pt.x + pt.y*pt.y + pt.z*pt.z);
  f[0]=pt.x; f[1]=pt.y; f[2]=pt.z; f[3]=pt.w; f[4]=dist;
  f[5]=pt.x-mx; f[6]=pt.y-my; f[7]=pt.z-mz;
  *vout = v;
}

// ---------------- pass 1: linear voxel id + counts + coord sums ----------------
__global__ __launch_bounds__(256) void k_lin(const float* __restrict__ pts,
                                             const int* __restrict__ coors,
                                             u32* __restrict__ lin,
                                             u32* __restrict__ counts,
                                             float* __restrict__ vsum){
  int p = blockIdx.x*256 + threadIdx.x;
  int4 c = ((const int4*)coors)[p];
  u32 v = ((u32)((c.x*FF + c.y)*HH + c.z))*WW + (u32)c.w;
  lin[p] = v;
  atomicAdd(&counts[v], 1u);
  float4 pt = ((const float4*)pts)[p];
  atomicAdd(&vsum[v*3+0], pt.x);
  atomicAdd(&vsum[v*3+1], pt.y);
  atomicAdd(&vsum[v*3+2], pt.z);
}

// ---------------- counting-sort scan ----------------
__global__ __launch_bounds__(256) void k_scan_a(const u32* __restrict__ counts,
                                                u32* __restrict__ blockSums){
  __shared__ u32 lds[256];
  int b = blockIdx.x, t = threadIdx.x;
  uint4 c4 = ((const uint4*)counts)[b*256 + t];
  lds[t] = c4.x + c4.y + c4.z + c4.w;
  __syncthreads();
  for(int s=128; s>0; s>>=1){ if(t<s) lds[t] += lds[t+s]; __syncthreads(); }
  if(t==0) blockSums[b] = lds[0];
}

__global__ void k_scan_b(u32* blockSums){
  if(threadIdx.x==0){
    u32 run = 0;
    for(int i=0;i<256;i++){ u32 v = blockSums[i]; blockSums[i] = run; run += v; }
  }
}

__global__ __launch_bounds__(256) void k_scan_c(const u32* __restrict__ counts,
                                                const u32* __restrict__ blockSums,
                                                u32* __restrict__ offsets,
                                                u32* __restrict__ cursor){
  __shared__ u32 lds[256];
  int b = blockIdx.x, t = threadIdx.x;
  uint4 c4 = ((const uint4*)counts)[b*256 + t];
  u32 mysum = c4.x + c4.y + c4.z + c4.w;
  lds[t] = mysum;
  __syncthreads();
  for(int d=1; d<256; d<<=1){
    u32 v = (t>=d) ? lds[t-d] : 0u;
    __syncthreads();
    lds[t] += v;
    __syncthreads();
  }
  u32 off = blockSums[b] + (t>0 ? lds[t-1] : 0u);
  u32 base = (u32)(b*1024 + t*4);
  offsets[base+0]=off; cursor[base+0]=off; off += c4.x;
  offsets[base+1]=off; cursor[base+1]=off; off += c4.y;
  offsets[base+2]=off; cursor[base+2]=off; off += c4.z;
  offsets[base+3]=off; cursor[base+3]=off; off += c4.w;
  if(base+4 == SS) offsets[SS] = off;
}

__global__ __launch_bounds__(256) void k_scatter(const u32* __restrict__ lin,
                                                 u32* __restrict__ cursor,
                                                 u32* __restrict__ order){
  int p = blockIdx.x*256 + threadIdx.x;
  u32 v = lin[p];
  u32 pos = atomicAdd(&cursor[v], 1u);
  order[pos] = p;
}

// ---------------- weight prep: bf16 transposed ----------------
__global__ __launch_bounds__(256) void k_prep(const float* __restrict__ W2,
    const float* __restrict__ W3, const float* __restrict__ W4,
    const float* __restrict__ Wc,
    u16* __restrict__ W2t, u16* __restrict__ W3t, u16* __restrict__ W4t,
    u16* __restrict__ Wct){
  int i = blockIdx.x*256 + threadIdx.x;
  if(i < 8192){
    int k = i >> 7, n = i & 127;
    W2t[n*64 + k] = f2bf(W2[i]);
  } else if(i < 8192+32768){
    int j = i - 8192;
    int k = j >> 8, n = j & 255;
    W3t[n*128 + k] = f2bf(W3[j]);
  } else if(i < 8192+32768+65536){
    int j = i - (8192+32768);
    int k = j >> 8, n = j & 255;
    W4t[n*256 + k] = f2bf(W4[j]);
  } else if(i < 8192+32768+65536+16384){
    int j = i - (8192+32768+65536);
    int k = j >> 6, n = j & 63;
    Wct[n*256 + k] = f2bf(Wc[j]);
  }
}

// ---------------- stats0: channel sums of raw feats (proven) ----------------
__global__ __launch_bounds__(256) void k_stats0(const float* __restrict__ pts,
    const u32* __restrict__ lin, const u32* __restrict__ counts,
    const float* __restrict__ vsum, float* __restrict__ sum0, float* __restrict__ sq0){
  int p = blockIdx.x*256 + threadIdx.x;
  float f[8]; u32 v;
  point_feats(p, pts, lin, counts, vsum, f, &v);
  __shared__ float lsum[4][8], lsq[4][8];
  int lane = threadIdx.x & 63, wv = threadIdx.x >> 6;
  #pragma unroll
  for(int c=0;c<8;c++){
    float s = f[c], q = f[c]*f[c];
    #pragma unroll
    for(int d=32; d; d>>=1){ s += __shfl_xor(s,d); q += __shfl_xor(q,d); }
    if(lane==0){ lsum[wv][c]=s; lsq[wv][c]=q; }
  }
  __syncthreads();
  if(threadIdx.x<8){
    float s=0.f,q=0.f;
    for(int g=0;g<4;g++){ s+=lsum[g][threadIdx.x]; q+=lsq[g][threadIdx.x]; }
    atomicAdd(&sum0[threadIdx.x], s);
    atomicAdd(&sq0[threadIdx.x], q);
  }
}

// ---------------- fold BN stats -> (a,c) (proven) ----------------
__global__ void k_fold(const float* __restrict__ sum, const float* __restrict__ sq,
                       const float* __restrict__ g, const float* __restrict__ b,
                       float* __restrict__ a, float* __restrict__ c, int C){
  int i = blockIdx.x*64 + threadIdx.x;
  if(i < C){
    float m = sum[i]*(1.0f/NPTS);
    float v = sq[i]*(1.0f/NPTS) - m*m;
    v = fmaxf(v, 0.0f);
    float ai = g[i] / sqrtf(v + EPSV);
    a[i] = ai;
    c[i] = b[i] - m*ai;
  }
}

// ---------------- stats1: channel sums of z1 (scalar, proven) ----------------
__global__ __launch_bounds__(256) void k_stats1(const float* __restrict__ pts,
    const u32* __restrict__ lin, const u32* __restrict__ counts,
    const float* __restrict__ vsum,
    const float* __restrict__ a0, const float* __restrict__ c0,
    const float* __restrict__ W1, float* __restrict__ sum1, float* __restrict__ sq1){
  __shared__ float ws[4][64], wq[4][64];
  int t = threadIdx.x;
  int p = blockIdx.x*256 + t;
  float f[8]; u32 v;
  point_feats(p, pts, lin, counts, vsum, f, &v);
  float y0[8];
  #pragma unroll
  for(int k=0;k<8;k++) y0[k] = a0[k]*f[k] + c0[k];
  float z[64];
  #pragma unroll
  for(int j=0;j<64;j++){
    float s=0.f;
    #pragma unroll
    for(int k=0;k<8;k++) s += y0[k]*W1[k*64+j];
    z[j]=s;
  }
  int lane = t&63, wv = t>>6;
  float ks=0.f, kq=0.f;
  #pragma unroll
  for(int c=0;c<64;c++){
    float s=z[c], q=z[c]*z[c];
    #pragma unroll
    for(int d=1; d<64; d<<=1){ s+=__shfl_xor(s,d); q+=__shfl_xor(q,d); }
    if(lane==c){ ks=s; kq=q; }
  }
  ws[wv][lane]=ks; wq[wv][lane]=kq;
  __syncthreads();
  if(t<64){
    float S=ws[0][t]+ws[1][t]+ws[2][t]+ws[3][t];
    float Q=wq[0][t]+wq[1][t]+wq[2][t]+wq[3][t];
    atomicAdd(&sum1[t],S); atomicAdd(&sq1[t],Q);
  }
}

// ---------------- mstats2: z2 stats via MFMA (mega2's proven L1/L2 code) ----------
__global__ __launch_bounds__(256,2) void k_mstats2(
    const float* __restrict__ pts, const u32* __restrict__ lin,
    const u32* __restrict__ counts, const float* __restrict__ vsum,
    const float* __restrict__ a0, const float* __restrict__ c0,
    const float* __restrict__ a1, const float* __restrict__ c1,
    const float* __restrict__ W1, const u16* __restrict__ W2t,
    float* __restrict__ sum2, float* __restrict__ sq2){
  __shared__ u16 T1[256*72];
  int tid = threadIdx.x, lane = tid&63, wid = tid>>6, l15 = lane&15, lg = lane>>4;
  float s2[2] = {0.f,0.f}, q2[2] = {0.f,0.f};

  for(int cch=0; cch<4; cch++){
    int p = blockIdx.x*1024 + cch*256 + tid;
    float f[8]; u32 v;
    point_feats(p, pts, lin, counts, vsum, f, &v);
    float y0[8];
    #pragma unroll
    for(int k=0;k<8;k++) y0[k] = a0[k]*f[k] + c0[k];
    u32 pk[32];
    #pragma unroll
    for(int jj=0;jj<32;jj++){
      float s0=0.f, s1=0.f;
      #pragma unroll
      for(int k=0;k<8;k++){ s0 += y0[k]*W1[k*64+2*jj]; s1 += y0[k]*W1[k*64+2*jj+1]; }
      float v0f = fmaxf(a1[2*jj]*s0   + c1[2*jj],   0.f);
      float v1f = fmaxf(a1[2*jj+1]*s1 + c1[2*jj+1], 0.f);
      pk[jj] = (u32)f2bf(v0f) | ((u32)f2bf(v1f)<<16);
    }
    __syncthreads();   // previous chunk's MFMA reads of T1 complete
    {
      uint4* dst = (uint4*)&T1[tid*72];
      #pragma unroll
      for(int q=0;q<8;q++) dst[q] = make_uint4(pk[4*q],pk[4*q+1],pk[4*q+2],pk[4*q+3]);
    }
    __syncthreads();
    #pragma unroll
    for(int ci=0; ci<2; ci++){
      int ch = (wid + 4*ci)*16 + l15;
      const u16* wb = W2t + (size_t)ch*64 + lg*8;
      bf16x8 b0 = *(const bf16x8*)(wb);
      bf16x8 b1 = *(const bf16x8*)(wb + 32);
      for(int rt=0; rt<16; rt++){
        const u16* ap = T1 + (rt*16 + l15)*72 + lg*8;
        bf16x8 af0 = *(const bf16x8*)(ap);
        bf16x8 af1 = *(const bf16x8*)(ap + 32);
        f32x4 acc = {0.f,0.f,0.f,0.f};
        acc = __builtin_amdgcn_mfma_f32_16x16x32_bf16(af0, b0, acc, 0,0,0);
        acc = __builtin_amdgcn_mfma_f32_16x16x32_bf16(af1, b1, acc, 0,0,0);
        #pragma unroll
        for(int i=0;i<4;i++){ s2[ci] += acc[i]; q2[ci] += acc[i]*acc[i]; }
      }
    }
  }
  #pragma unroll
  for(int ci=0; ci<2; ci++){
    float s = s2[ci], q = q2[ci];
    s += __shfl_xor(s,16); s += __shfl_xor(s,32);
    q += __shfl_xor(q,16); q += __shfl_xor(q,32);
    if(lg == 0){
      int ch = (wid + 4*ci)*16 + l15;
      atomicAdd(&sum2[ch], s);
      atomicAdd(&sq2[ch], q);
    }
  }
}

// ---------------- mstats3: z3 stats via MFMA (mega2's proven L1/L2/L3 code) -------
__global__ __launch_bounds__(256,1) void k_mstats3(
    const float* __restrict__ pts, const u32* __restrict__ lin,
    const u32* __restrict__ counts, const float* __restrict__ vsum,
    const float* __restrict__ a0, const float* __restrict__ c0,
    const float* __restrict__ a1, const float* __restrict__ c1,
    const float* __restrict__ a2, const float* __restrict__ c2,
    const float* __restrict__ W1, const u16* __restrict__ W2t,
    const u16* __restrict__ W3t,
    float* __restrict__ sum3, float* __restrict__ sq3){
  __shared__ u16 T1[256*72];
  __shared__ u16 T2[256*136];
  int tid = threadIdx.x, lane = tid&63, wid = tid>>6, l15 = lane&15, lg = lane>>4;
  float s3[4] = {0.f,0.f,0.f,0.f}, q3[4] = {0.f,0.f,0.f,0.f};

  for(int cch=0; cch<4; cch++){
    int p = blockIdx.x*1024 + cch*256 + tid;
    float f[8]; u32 v;
    point_feats(p, pts, lin, counts, vsum, f, &v);
    float y0[8];
    #pragma unroll
    for(int k=0;k<8;k++) y0[k] = a0[k]*f[k] + c0[k];
    u32 pk[32];
    #pragma unroll
    for(int jj=0;jj<32;jj++){
      float s0=0.f, s1=0.f;
      #pragma unroll
      for(int k=0;k<8;k++){ s0 += y0[k]*W1[k*64+2*jj]; s1 += y0[k]*W1[k*64+2*jj+1]; }
      float v0f = fmaxf(a1[2*jj]*s0   + c1[2*jj],   0.f);
      float v1f = fmaxf(a1[2*jj+1]*s1 + c1[2*jj+1], 0.f);
      pk[jj] = (u32)f2bf(v0f) | ((u32)f2bf(v1f)<<16);
    }
    __syncthreads();   // previous chunk's L3 reads of T2 / L2 reads of T1 complete
    {
      uint4* dst = (uint4*)&T1[tid*72];
      #pragma unroll
      for(int q=0;q<8;q++) dst[q] = make_uint4(pk[4*q],pk[4*q+1],pk[4*q+2],pk[4*q+3]);
    }
    __syncthreads();
    // L2: T1(256x64) @ W2t -> bn2relu -> T2(256x128)
    #pragma unroll
    for(int ci=0; ci<2; ci++){
      int ch = (wid + 4*ci)*16 + l15;
      const u16* wb = W2t + (size_t)ch*64 + lg*8;
      bf16x8 b0 = *(const bf16x8*)(wb);
      bf16x8 b1 = *(const bf16x8*)(wb + 32);
      float a2v = a2[ch], c2v = c2[ch];
      for(int rt=0; rt<16; rt++){
        const u16* ap = T1 + (rt*16 + l15)*72 + lg*8;
        bf16x8 af0 = *(const bf16x8*)(ap);
        bf16x8 af1 = *(const bf16x8*)(ap + 32);
        f32x4 acc = {0.f,0.f,0.f,0.f};
        acc = __builtin_amdgcn_mfma_f32_16x16x32_bf16(af0, b0, acc, 0,0,0);
        acc = __builtin_amdgcn_mfma_f32_16x16x32_bf16(af1, b1, acc, 0,0,0);
        int rbase = rt*16 + lg*4;
        #pragma unroll
        for(int i=0;i<4;i++)
          T2[(rbase+i)*136 + ch] = f2bf(fmaxf(a2v*acc[i] + c2v, 0.f));
      }
    }
    __syncthreads();
    // L3: z3 = T2(256x128) @ W3t, accumulate sum/sumsq only
    #pragma unroll
    for(int ci=0; ci<4; ci++){
      int ch = (wid + 4*ci)*16 + l15;
      const u16* wb = W3t + (size_t)ch*128 + lg*8;
      bf16x8 b[4];
      #pragma unroll
      for(int ks=0; ks<4; ks++) b[ks] = *(const bf16x8*)(wb + ks*32);
      for(int rt=0; rt<16; rt++){
        const u16* ap = T2 + (rt*16 + l15)*136 + lg*8;
        f32x4 acc = {0.f,0.f,0.f,0.f};
        #pragma unroll
        for(int ks=0; ks<4; ks++){
          bf16x8 af = *(const bf16x8*)(ap + ks*32);
          acc = __builtin_amdgcn_mfma_f32_16x16x32_bf16(af, b[ks], acc, 0,0,0);
        }
        #pragma unroll
        for(int i=0;i<4;i++){ s3[ci] += acc[i]; q3[ci] += acc[i]*acc[i]; }
      }
    }
  }
  #pragma unroll
  for(int ci=0; ci<4; ci++){
    float s = s3[ci], q = q3[ci];
    s += __shfl_xor(s,16); s += __shfl_xor(s,32);
    q += __shfl_xor(q,16); q += __shfl_xor(q,32);
    if(lg == 0){
      int ch = (wid + 4*ci)*16 + l15;
      atomicAdd(&sum3[ch], s);
      atomicAdd(&sq3[ch], q);
    }
  }
}

// ---------------- mega2: MFMA chain + segmax + voxel GEMM (proven) ----------------
__global__ __launch_bounds__(256,1) void k_mega2(
    const float* __restrict__ pts, const u32* __restrict__ lin,
    const u32* __restrict__ counts, const float* __restrict__ vsum,
    const u32* __restrict__ offsets, const u32* __restrict__ order,
    const float* __restrict__ a0, const float* __restrict__ c0,
    const float* __restrict__ a1, const float* __restrict__ c1,
    const float* __restrict__ a2, const float* __restrict__ c2,
    const float* __restrict__ a3, const float* __restrict__ c3,
    const float* __restrict__ W1,
    const u16* __restrict__ W2t, const u16* __restrict__ W3t,
    const u16* __restrict__ W4t, const u16* __restrict__ Wct,
    const float* __restrict__ b4, const float* __restrict__ bc,
    u16* __restrict__ comp){
  __shared__ __align__(16) char SM[115712];
  u16* T1   = (u16*)(SM);                 // [144][72]
  u16* T3   = (u16*)(SM);                 // [144][264]
  u16* T2   = (u16*)(SM + 76032);         // [144][136]
  u32* vmax = (u32*)(SM + 76032);         // [96][66]
  u16* TA   = (u16*)(SM + 76032 + 25344); // [96][72]
  u16* rowvox = (u16*)(SM + 115200);      // [144]
  u16* nzf  = (u16*)(SM + 115200 + 288);  // [96]
  u32* hdr  = (u32*)(SM + 115200 + 480);  // [4]

  int tid = threadIdx.x, lane = tid & 63, wid = tid >> 6;
  int l15 = lane & 15, lg = lane >> 4;

  if(tid == 0){
    u32 t0 = (u32)blockIdx.x * 128u;
    u32 lo=0, hi=SS;
    while(lo<hi){ u32 mid=(lo+hi)>>1; if(offsets[mid] < t0) lo=mid+1; else hi=mid; }
    u32 vlo = lo, vhi;
    if(blockIdx.x == NB-1) vhi = SS;
    else {
      u32 t1 = t0 + 128u;
      lo = vlo; hi = SS;
      while(lo<hi){ u32 mid=(lo+hi)>>1; if(offsets[mid] < t1) lo=mid+1; else hi=mid; }
      vhi = lo;
    }
    hdr[0]=vlo; hdr[1]=vhi; hdr[2]=offsets[vlo]; hdr[3]=offsets[vhi];
  }
  __syncthreads();
  u32 vlo=hdr[0], vhi=hdr[1], start=hdr[2], end=hdr[3];
  int R = (int)(end - start); if(R > RCAP) R = RCAP;
  int V = (int)(vhi - vlo);   if(V > VCAP) V = VCAP;

  for(int v=tid; v<VCAP; v+=256)
    nzf[v] = (v < V && offsets[vlo+v+1] > offsets[vlo+v]) ? 1 : 0;

  for(int r=tid; r<RCAP; r+=256){
    uint4* dst = (uint4*)&T1[r*72];
    if(r < R){
      u32 p = order[start + r];
      float4 pt = ((const float4*)pts)[p];
      u32 v = lin[p];
      float cnt = fmaxf((float)counts[v], 1.0f);
      float inv = 1.0f/cnt;
      float mx = vsum[v*3+0]*inv, my = vsum[v*3+1]*inv, mz = vsum[v*3+2]*inv;
      float dist = sqrtf(pt.x*pt.x + pt.y*pt.y + pt.z*pt.z);
      u32 dv = v - vlo; if(dv > (u32)(VCAP-1)) dv = VCAP-1;
      rowvox[r] = (u16)dv;
      float y0[8] = {pt.x, pt.y, pt.z, pt.w, dist, pt.x-mx, pt.y-my, pt.z-mz};
      #pragma unroll
      for(int k=0;k<8;k++) y0[k] = a0[k]*y0[k] + c0[k];
      u32 pk[32];
      #pragma unroll
      for(int jj=0; jj<32; jj++){
        float s0=0.f, s1=0.f;
        #pragma unroll
        for(int k=0;k<8;k++){ s0 += y0[k]*W1[k*64+2*jj]; s1 += y0[k]*W1[k*64+2*jj+1]; }
        float v0f = fmaxf(a1[2*jj]*s0   + c1[2*jj],   0.f);
        float v1f = fmaxf(a1[2*jj+1]*s1 + c1[2*jj+1], 0.f);
        pk[jj] = (u32)f2bf(v0f) | ((u32)f2bf(v1f)<<16);
      }
      #pragma unroll
      for(int q=0;q<8;q++) dst[q] = make_uint4(pk[4*q],pk[4*q+1],pk[4*q+2],pk[4*q+3]);
    } else {
      uint4 z = make_uint4(0,0,0,0);
      #pragma unroll
      for(int q=0;q<8;q++) dst[q] = z;
    }
  }
  __syncthreads();

  for(int ci=0; ci<2; ci++){
    int ct = wid + 4*ci;
    int ch = ct*16 + l15;
    const u16* wb = W2t + (size_t)ch*64 + lg*8;
    bf16x8 b0 = *(const bf16x8*)(wb);
    bf16x8 b1 = *(const bf16x8*)(wb + 32);
    float a2v = a2[ch], c2v = c2[ch];
    for(int rt=0; rt<9; rt++){
      const u16* ap = T1 + (rt*16 + l15)*72 + lg*8;
      bf16x8 af0 = *(const bf16x8*)(ap);
      bf16x8 af1 = *(const bf16x8*)(ap + 32);
      f32x4 acc = {0.f,0.f,0.f,0.f};
      acc = __builtin_amdgcn_mfma_f32_16x16x32_bf16(af0, b0, acc, 0,0,0);
      acc = __builtin_amdgcn_mfma_f32_16x16x32_bf16(af1, b1, acc, 0,0,0);
      int rbase = rt*16 + lg*4;
      #pragma unroll
      for(int i=0;i<4;i++)
        T2[(rbase+i)*136 + ch] = f2bf(fmaxf(a2v*acc[i] + c2v, 0.f));
    }
  }
  __syncthreads();

  for(int ci=0; ci<4; ci++){
    int ct = wid + 4*ci;
    int ch = ct*16 + l15;
    const u16* wb = W3t + (size_t)ch*128 + lg*8;
    bf16x8 b[4];
    #pragma unroll
    for(int ks=0; ks<4; ks++) b[ks] = *(const bf16x8*)(wb + ks*32);
    float a3v = a3[ch], c3v = c3[ch];
    for(int rt=0; rt<9; rt++){
      const u16* ap = T2 + (rt*16 + l15)*136 + lg*8;
      f32x4 acc = {0.f,0.f,0.f,0.f};
      #pragma unroll
      for(int ks=0; ks<4; ks++){
        bf16x8 af = *(const bf16x8*)(ap + ks*32);
        acc = __builtin_amdgcn_mfma_f32_16x16x32_bf16(af, b[ks], acc, 0,0,0);
      }
      int rbase = rt*16 + lg*4;
      #pragma unroll
      for(int i=0;i<4;i++)
        T3[(rbase+i)*264 + ch] = f2bf(fmaxf(a3v*acc[i] + c3v, 0.f));
    }
  }
  __syncthreads();

  f32x4 acc6[6];
  #pragma unroll
  for(int i=0;i<6;i++) acc6[i] = (f32x4){0.f,0.f,0.f,0.f};
  int ch4 = wid*16 + l15;

  for(int oc=0; oc<4; oc++){
    for(int i=tid; i<VCAP*66; i+=256) vmax[i] = 0u;
    __syncthreads();
    {
      int chg = oc*64 + ch4;
      const u16* wb = W4t + (size_t)chg*256 + lg*8;
      bf16x8 b[8];
      #pragma unroll
      for(int ks=0; ks<8; ks++) b[ks] = *(const bf16x8*)(wb + ks*32);
      for(int rt=0; rt<9; rt++){
        const u16* ap = T3 + (rt*16 + l15)*264 + lg*8;
        f32x4 acc = {0.f,0.f,0.f,0.f};
        #pragma unroll
        for(int ks=0; ks<8; ks++){
          bf16x8 af = *(const bf16x8*)(ap + ks*32);
          acc = __builtin_amdgcn_mfma_f32_16x16x32_bf16(af, b[ks], acc, 0,0,0);
        }
        int rbase = rt*16 + lg*4;
        #pragma unroll
        for(int i=0;i<4;i++){
          int row = rbase + i;
          if(row < R)
            atomicMax(&vmax[(u32)rowvox[row]*66u + (u32)ch4], fkey(acc[i]));
        }
      }
    }
    __syncthreads();
    for(int i=tid; i<VCAP*64; i+=256){
      int v = i>>6, k = i&63;
      u16 val = 0;
      if(nzf[v]) val = f2bf(fdec(vmax[v*66+k]) + b4[oc*64+k]);
      TA[v*72+k] = val;
    }
    __syncthreads();
    {
      const u16* wb = Wct + (size_t)ch4*256 + oc*64 + lg*8;
      bf16x8 b0 = *(const bf16x8*)(wb);
      bf16x8 b1 = *(const bf16x8*)(wb + 32);
      #pragma unroll
      for(int vt=0; vt<6; vt++){
        const u16* ap = TA + (vt*16 + l15)*72 + lg*8;
        bf16x8 af0 = *(const bf16x8*)(ap);
        bf16x8 af1 = *(const bf16x8*)(ap + 32);
        acc6[vt] = __builtin_amdgcn_mfma_f32_16x16x32_bf16(af0, b0, acc6[vt], 0,0,0);
        acc6[vt] = __builtin_amdgcn_mfma_f32_16x16x32_bf16(af1, b1, acc6[vt], 0,0,0);
      }
    }
    __syncthreads();
  }

  {
    float bcv = bc[ch4];
    #pragma unroll
    for(int vt=0; vt<6; vt++){
      int vbase = vt*16 + lg*4;
      #pragma unroll
      for(int i=0;i<4;i++){
        int vox = vbase + i;
        if(vox < V){
          float val = nzf[vox] ? fmaxf(acc6[vt][i] + bcv, 0.f) : 0.f;
          comp[(size_t)(vlo+vox)*64 + ch4] = f2bf(val);
        }
      }
    }
  }
}

// ---------------- residual image from comp (proven) ----------------
__global__ __launch_bounds__(256) void k_resid(const u16* __restrict__ comp,
                                               float* __restrict__ out){
  __shared__ u32 cl[4*128*32];
  int t = threadIdx.x;
  int blk = blockIdx.x;
  int wq = blk & 3, h = (blk>>2) & 63, b = blk>>8;
  int w0 = wq*128;
  for(int fr=0; fr<4; fr++){
    const u32* src = (const u32*)comp + ((size_t)(((b*4+fr)*64 + h)*512 + w0))*32;
    for(int i=t; i<4096; i+=256){
      int vox = i>>5, wd = i&31;
      cl[fr*4096 + vox*32 + (wd ^ (vox&31))] = src[i];
    }
  }
  __syncthreads();
  int wl = t & 127, half = t >> 7;
  int mv = wl & 31;
  for(int ch = half; ch < 64; ch += 2){
    u32 wr3 = cl[3*4096 + wl*32 + ((ch>>1) ^ mv)];
    float r3 = bf2f((ch&1) ? (u16)(wr3>>16) : (u16)(wr3&0xFFFFu));
    #pragma unroll
    for(int fr=0; fr<3; fr++){
      u32 wrf = cl[fr*4096 + wl*32 + ((ch>>1) ^ mv)];
      float vf = bf2f((ch&1) ? (u16)(wrf>>16) : (u16)(wrf&0xFFFFu));
      out[(((size_t)(b*192 + fr*64 + ch))*64 + h)*512 + w0 + wl] = r3 - vf;
    }
  }
}

// ------------------------------- launcher -------------------------------------
extern "C" void kernel_launch(void* const* d_in, const int* in_sizes, int n_in,
                              void* d_out, int out_size, void* d_ws, size_t ws_size,
                              hipStream_t stream){
  const float* pts  = (const float*)d_in[0];
  const int*  coors = (const int*)d_in[1];
  const float* g0 = (const float*)d_in[2];
  const float* b0 = (const float*)d_in[3];
  const float* W1 = (const float*)d_in[4];
  const float* g1 = (const float*)d_in[5];
  const float* b1 = (const float*)d_in[6];
  const float* W2 = (const float*)d_in[7];
  const float* g2 = (const float*)d_in[8];
  const float* b2 = (const float*)d_in[9];
  const float* W3 = (const float*)d_in[10];
  const float* g3 = (const float*)d_in[11];
  const float* b3 = (const float*)d_in[12];
  const float* W4 = (const float*)d_in[13];
  const float* b4 = (const float*)d_in[14];
  const float* Wc = (const float*)d_in[15];
  const float* bc = (const float*)d_in[16];
  float* out = (float*)d_out;
  (void)in_sizes; (void)n_in; (void)out_size; (void)ws_size;

  char* ws = (char*)d_ws;
  size_t off = 0;
  auto alloc = [&](size_t bytes)->void*{
    void* p = ws + off;
    off += (bytes + 255) & ~(size_t)255;
    return p;
  };
  u32*  counts  = (u32*)alloc((size_t)SS*4);
  float* vsum   = (float*)alloc((size_t)SS*3*4);
  float* stats  = (float*)alloc(8192);
  size_t zero_bytes = off;
  u32*  lin     = (u32*)alloc((size_t)NPTS*4);
  u32*  offsets = (u32*)alloc((size_t)(SS+1)*4);
  u32*  cursor  = (u32*)alloc((size_t)SS*4);
  u32*  order   = (u32*)alloc((size_t)NPTS*4);
  u32*  blockSums = (u32*)alloc(1024);
  u16*  comp    = (u16*)alloc((size_t)SS*64*2);
  u16*  W2t = (u16*)alloc(8192*2);
  u16*  W3t = (u16*)alloc(32768*2);
  u16*  W4t = (u16*)alloc(65536*2);
  u16*  Wct = (u16*)alloc(16384*2);

  float* sum0=stats+0,   *sq0=stats+8,    *a0=stats+16,   *c0=stats+24;
  float* sum1=stats+32,  *sq1=stats+96,   *a1=stats+160,  *c1=stats+224;
  float* sum2=stats+288, *sq2=stats+416,  *a2=stats+544,  *c2=stats+672;
  float* sum3=stats+800, *sq3=stats+1056, *a3=stats+1312, *c3=stats+1568;

  hipMemsetAsync(d_ws, 0, zero_bytes, stream);

  k_prep   <<<480, 256,0,stream>>>(W2, W3, W4, Wc, W2t, W3t, W4t, Wct);
  k_lin    <<<2048,256,0,stream>>>(pts, coors, lin, counts, vsum);
  k_scan_a <<<256, 256,0,stream>>>(counts, blockSums);
  k_scan_b <<<1,   64, 0,stream>>>(blockSums);
  k_scan_c <<<256, 256,0,stream>>>(counts, blockSums, offsets, cursor);
  k_scatter<<<2048,256,0,stream>>>(lin, cursor, order);

  k_stats0 <<<2048,256,0,stream>>>(pts, lin, counts, vsum, sum0, sq0);
  k_fold   <<<1,   64, 0,stream>>>(sum0, sq0, g0, b0, a0, c0, 8);
  k_stats1 <<<2048,256,0,stream>>>(pts, lin, counts, vsum, a0, c0, W1, sum1, sq1);
  k_fold   <<<1,   64, 0,stream>>>(sum1, sq1, g1, b1, a1, c1, 64);
  k_mstats2<<<512, 256,0,stream>>>(pts, lin, counts, vsum, a0,c0,a1,c1, W1, W2t, sum2, sq2);
  k_fold   <<<2,   64, 0,stream>>>(sum2, sq2, g2, b2, a2, c2, 128);
  k_mstats3<<<512, 256,0,stream>>>(pts, lin, counts, vsum, a0,c0,a1,c1,a2,c2, W1, W2t, W3t, sum3, sq3);
  k_fold   <<<4,   64, 0,stream>>>(sum3, sq3, g3, b3, a3, c3, 256);

  k_mega2  <<<NB,  256,0,stream>>>(pts, lin, counts, vsum, offsets, order,
                                   a0,c0,a1,c1,a2,c2,a3,c3,
                                   W1, W2t, W3t, W4t, Wct, b4, bc, comp);
  k_resid  <<<512, 256,0,stream>>>(comp, out);
}

// Round 6
// 1316.227 us; speedup vs baseline: 9.9549x; 1.0887x over previous
//
#include <hip/hip_runtime.h>
#include <hip/hip_bf16.h>
#include <stdint.h>

typedef unsigned int u32;
typedef unsigned short u16;
typedef __attribute__((ext_vector_type(8))) short bf16x8;
typedef __attribute__((ext_vector_type(4))) float f32x4;

#define NPTS 524288
#define FF 4
#define HH 64
#define WW 512
#define SS 262144
#define EPSV 1e-5f
#define NB 8192      // 64 points per block
#define RCAP 80      // 64 + straddle slack
#define VCAP 80

__device__ __forceinline__ float bf2f(u16 h){ return __uint_as_float(((u32)h)<<16); }
__device__ __forceinline__ u16 f2bf(float f){
  u32 u = __float_as_uint(f);
  return (u16)((u + 0x7FFFu + ((u>>16)&1u)) >> 16);   // RNE (monotone)
}

__device__ __forceinline__ void point_feats(int p, const float* __restrict__ pts,
    const u32* __restrict__ lin, const u32* __restrict__ counts,
    const float* __restrict__ vsum, float f[8], u32* vout){
  float4 pt = ((const float4*)pts)[p];
  u32 v = lin[p];
  float cnt = fmaxf((float)counts[v], 1.0f);
  float inv = 1.0f/cnt;
  float mx = vsum[v*3+0]*inv, my = vsum[v*3+1]*inv, mz = vsum[v*3+2]*inv;
  float dist = sqrtf(pt.x*pt.x + pt.y*pt.y + pt.z*pt.z);
  f[0]=pt.x; f[1]=pt.y; f[2]=pt.z; f[3]=pt.w; f[4]=dist;
  f[5]=pt.x-mx; f[6]=pt.y-my; f[7]=pt.z-mz;
  *vout = v;
}

// ---------------- pass 1: linear voxel id + counts + coord sums ----------------
__global__ __launch_bounds__(256) void k_lin(const float* __restrict__ pts,
                                             const int* __restrict__ coors,
                                             u32* __restrict__ lin,
                                             u32* __restrict__ counts,
                                             float* __restrict__ vsum){
  int p = blockIdx.x*256 + threadIdx.x;
  int4 c = ((const int4*)coors)[p];
  u32 v = ((u32)((c.x*FF + c.y)*HH + c.z))*WW + (u32)c.w;
  lin[p] = v;
  atomicAdd(&counts[v], 1u);
  float4 pt = ((const float4*)pts)[p];
  atomicAdd(&vsum[v*3+0], pt.x);
  atomicAdd(&vsum[v*3+1], pt.y);
  atomicAdd(&vsum[v*3+2], pt.z);
}

// ---------------- counting-sort scan ----------------
__global__ __launch_bounds__(256) void k_scan_a(const u32* __restrict__ counts,
                                                u32* __restrict__ blockSums){
  __shared__ u32 lds[256];
  int b = blockIdx.x, t = threadIdx.x;
  uint4 c4 = ((const uint4*)counts)[b*256 + t];
  lds[t] = c4.x + c4.y + c4.z + c4.w;
  __syncthreads();
  for(int s=128; s>0; s>>=1){ if(t<s) lds[t] += lds[t+s]; __syncthreads(); }
  if(t==0) blockSums[b] = lds[0];
}

__global__ void k_scan_b(u32* blockSums){
  if(threadIdx.x==0){
    u32 run = 0;
    for(int i=0;i<256;i++){ u32 v = blockSums[i]; blockSums[i] = run; run += v; }
  }
}

__global__ __launch_bounds__(256) void k_scan_c(const u32* __restrict__ counts,
                                                const u32* __restrict__ blockSums,
                                                u32* __restrict__ offsets,
                                                u32* __restrict__ cursor){
  __shared__ u32 lds[256];
  int b = blockIdx.x, t = threadIdx.x;
  uint4 c4 = ((const uint4*)counts)[b*256 + t];
  u32 mysum = c4.x + c4.y + c4.z + c4.w;
  lds[t] = mysum;
  __syncthreads();
  for(int d=1; d<256; d<<=1){
    u32 v = (t>=d) ? lds[t-d] : 0u;
    __syncthreads();
    lds[t] += v;
    __syncthreads();
  }
  u32 off = blockSums[b] + (t>0 ? lds[t-1] : 0u);
  u32 base = (u32)(b*1024 + t*4);
  offsets[base+0]=off; cursor[base+0]=off; off += c4.x;
  offsets[base+1]=off; cursor[base+1]=off; off += c4.y;
  offsets[base+2]=off; cursor[base+2]=off; off += c4.z;
  offsets[base+3]=off; cursor[base+3]=off; off += c4.w;
  if(base+4 == SS) offsets[SS] = off;
}

__global__ __launch_bounds__(256) void k_scatter(const u32* __restrict__ lin,
                                                 u32* __restrict__ cursor,
                                                 u32* __restrict__ order){
  int p = blockIdx.x*256 + threadIdx.x;
  u32 v = lin[p];
  u32 pos = atomicAdd(&cursor[v], 1u);
  order[pos] = p;
}

// ---------------- weight prep: bf16 transposed ----------------
__global__ __launch_bounds__(256) void k_prep(const float* __restrict__ W2,
    const float* __restrict__ W3, const float* __restrict__ W4,
    const float* __restrict__ Wc,
    u16* __restrict__ W2t, u16* __restrict__ W3t, u16* __restrict__ W4t,
    u16* __restrict__ Wct){
  int i = blockIdx.x*256 + threadIdx.x;
  if(i < 8192){
    int k = i >> 7, n = i & 127;
    W2t[n*64 + k] = f2bf(W2[i]);
  } else if(i < 8192+32768){
    int j = i - 8192;
    int k = j >> 8, n = j & 255;
    W3t[n*128 + k] = f2bf(W3[j]);
  } else if(i < 8192+32768+65536){
    int j = i - (8192+32768);
    int k = j >> 8, n = j & 255;
    W4t[n*256 + k] = f2bf(W4[j]);
  } else if(i < 8192+32768+65536+16384){
    int j = i - (8192+32768+65536);
    int k = j >> 6, n = j & 63;
    Wct[n*256 + k] = f2bf(Wc[j]);
  }
}

// ---------------- stats0 (proven) ----------------
__global__ __launch_bounds__(256) void k_stats0(const float* __restrict__ pts,
    const u32* __restrict__ lin, const u32* __restrict__ counts,
    const float* __restrict__ vsum, float* __restrict__ sum0, float* __restrict__ sq0){
  int p = blockIdx.x*256 + threadIdx.x;
  float f[8]; u32 v;
  point_feats(p, pts, lin, counts, vsum, f, &v);
  __shared__ float lsum[4][8], lsq[4][8];
  int lane = threadIdx.x & 63, wv = threadIdx.x >> 6;
  #pragma unroll
  for(int c=0;c<8;c++){
    float s = f[c], q = f[c]*f[c];
    #pragma unroll
    for(int d=32; d; d>>=1){ s += __shfl_xor(s,d); q += __shfl_xor(q,d); }
    if(lane==0){ lsum[wv][c]=s; lsq[wv][c]=q; }
  }
  __syncthreads();
  if(threadIdx.x<8){
    float s=0.f,q=0.f;
    for(int g=0;g<4;g++){ s+=lsum[g][threadIdx.x]; q+=lsq[g][threadIdx.x]; }
    atomicAdd(&sum0[threadIdx.x], s);
    atomicAdd(&sq0[threadIdx.x], q);
  }
}

// ---------------- fold BN stats -> (a,c) (proven) ----------------
__global__ void k_fold(const float* __restrict__ sum, const float* __restrict__ sq,
                       const float* __restrict__ g, const float* __restrict__ b,
                       float* __restrict__ a, float* __restrict__ c, int C){
  int i = blockIdx.x*64 + threadIdx.x;
  if(i < C){
    float m = sum[i]*(1.0f/NPTS);
    float v = sq[i]*(1.0f/NPTS) - m*m;
    v = fmaxf(v, 0.0f);
    float ai = g[i] / sqrtf(v + EPSV);
    a[i] = ai;
    c[i] = b[i] - m*ai;
  }
}

// ---------------- stats1 (scalar, proven) ----------------
__global__ __launch_bounds__(256) void k_stats1(const float* __restrict__ pts,
    const u32* __restrict__ lin, const u32* __restrict__ counts,
    const float* __restrict__ vsum,
    const float* __restrict__ a0, const float* __restrict__ c0,
    const float* __restrict__ W1, float* __restrict__ sum1, float* __restrict__ sq1){
  __shared__ float ws[4][64], wq[4][64];
  int t = threadIdx.x;
  int p = blockIdx.x*256 + t;
  float f[8]; u32 v;
  point_feats(p, pts, lin, counts, vsum, f, &v);
  float y0[8];
  #pragma unroll
  for(int k=0;k<8;k++) y0[k] = a0[k]*f[k] + c0[k];
  float z[64];
  #pragma unroll
  for(int j=0;j<64;j++){
    float s=0.f;
    #pragma unroll
    for(int k=0;k<8;k++) s += y0[k]*W1[k*64+j];
    z[j]=s;
  }
  int lane = t&63, wv = t>>6;
  float ks=0.f, kq=0.f;
  #pragma unroll
  for(int c=0;c<64;c++){
    float s=z[c], q=z[c]*z[c];
    #pragma unroll
    for(int d=1; d<64; d<<=1){ s+=__shfl_xor(s,d); q+=__shfl_xor(q,d); }
    if(lane==c){ ks=s; kq=q; }
  }
  ws[wv][lane]=ks; wq[wv][lane]=kq;
  __syncthreads();
  if(t<64){
    float S=ws[0][t]+ws[1][t]+ws[2][t]+ws[3][t];
    float Q=wq[0][t]+wq[1][t]+wq[2][t]+wq[3][t];
    atomicAdd(&sum1[t],S); atomicAdd(&sq1[t],Q);
  }
}

// ---------------- mstats2: z2 stats via MFMA (proven) ----------
__global__ __launch_bounds__(256,2) void k_mstats2(
    const float* __restrict__ pts, const u32* __restrict__ lin,
    const u32* __restrict__ counts, const float* __restrict__ vsum,
    const float* __restrict__ a0, const float* __restrict__ c0,
    const float* __restrict__ a1, const float* __restrict__ c1,
    const float* __restrict__ W1, const u16* __restrict__ W2t,
    float* __restrict__ sum2, float* __restrict__ sq2){
  __shared__ u16 T1[256*72];
  int tid = threadIdx.x, lane = tid&63, wid = tid>>6, l15 = lane&15, lg = lane>>4;
  float s2[2] = {0.f,0.f}, q2[2] = {0.f,0.f};

  for(int cch=0; cch<4; cch++){
    int p = blockIdx.x*1024 + cch*256 + tid;
    float f[8]; u32 v;
    point_feats(p, pts, lin, counts, vsum, f, &v);
    float y0[8];
    #pragma unroll
    for(int k=0;k<8;k++) y0[k] = a0[k]*f[k] + c0[k];
    u32 pk[32];
    #pragma unroll
    for(int jj=0;jj<32;jj++){
      float s0=0.f, s1=0.f;
      #pragma unroll
      for(int k=0;k<8;k++){ s0 += y0[k]*W1[k*64+2*jj]; s1 += y0[k]*W1[k*64+2*jj+1]; }
      float v0f = fmaxf(a1[2*jj]*s0   + c1[2*jj],   0.f);
      float v1f = fmaxf(a1[2*jj+1]*s1 + c1[2*jj+1], 0.f);
      pk[jj] = (u32)f2bf(v0f) | ((u32)f2bf(v1f)<<16);
    }
    __syncthreads();
    {
      uint4* dst = (uint4*)&T1[tid*72];
      #pragma unroll
      for(int q=0;q<8;q++) dst[q] = make_uint4(pk[4*q],pk[4*q+1],pk[4*q+2],pk[4*q+3]);
    }
    __syncthreads();
    #pragma unroll
    for(int ci=0; ci<2; ci++){
      int ch = (wid + 4*ci)*16 + l15;
      const u16* wb = W2t + (size_t)ch*64 + lg*8;
      bf16x8 b0 = *(const bf16x8*)(wb);
      bf16x8 b1 = *(const bf16x8*)(wb + 32);
      for(int rt=0; rt<16; rt++){
        const u16* ap = T1 + (rt*16 + l15)*72 + lg*8;
        bf16x8 af0 = *(const bf16x8*)(ap);
        bf16x8 af1 = *(const bf16x8*)(ap + 32);
        f32x4 acc = {0.f,0.f,0.f,0.f};
        acc = __builtin_amdgcn_mfma_f32_16x16x32_bf16(af0, b0, acc, 0,0,0);
        acc = __builtin_amdgcn_mfma_f32_16x16x32_bf16(af1, b1, acc, 0,0,0);
        #pragma unroll
        for(int i=0;i<4;i++){ s2[ci] += acc[i]; q2[ci] += acc[i]*acc[i]; }
      }
    }
  }
  #pragma unroll
  for(int ci=0; ci<2; ci++){
    float s = s2[ci], q = q2[ci];
    s += __shfl_xor(s,16); s += __shfl_xor(s,32);
    q += __shfl_xor(q,16); q += __shfl_xor(q,32);
    if(lg == 0){
      int ch = (wid + 4*ci)*16 + l15;
      atomicAdd(&sum2[ch], s);
      atomicAdd(&sq2[ch], q);
    }
  }
}

// ---------------- mstats3: z3 stats via MFMA (proven) -------
__global__ __launch_bounds__(256,1) void k_mstats3(
    const float* __restrict__ pts, const u32* __restrict__ lin,
    const u32* __restrict__ counts, const float* __restrict__ vsum,
    const float* __restrict__ a0, const float* __restrict__ c0,
    const float* __restrict__ a1, const float* __restrict__ c1,
    const float* __restrict__ a2, const float* __restrict__ c2,
    const float* __restrict__ W1, const u16* __restrict__ W2t,
    const u16* __restrict__ W3t,
    float* __restrict__ sum3, float* __restrict__ sq3){
  __shared__ u16 T1[256*72];
  __shared__ u16 T2[256*136];
  int tid = threadIdx.x, lane = tid&63, wid = tid>>6, l15 = lane&15, lg = lane>>4;
  float s3[4] = {0.f,0.f,0.f,0.f}, q3[4] = {0.f,0.f,0.f,0.f};

  for(int cch=0; cch<4; cch++){
    int p = blockIdx.x*1024 + cch*256 + tid;
    float f[8]; u32 v;
    point_feats(p, pts, lin, counts, vsum, f, &v);
    float y0[8];
    #pragma unroll
    for(int k=0;k<8;k++) y0[k] = a0[k]*f[k] + c0[k];
    u32 pk[32];
    #pragma unroll
    for(int jj=0;jj<32;jj++){
      float s0=0.f, s1=0.f;
      #pragma unroll
      for(int k=0;k<8;k++){ s0 += y0[k]*W1[k*64+2*jj]; s1 += y0[k]*W1[k*64+2*jj+1]; }
      float v0f = fmaxf(a1[2*jj]*s0   + c1[2*jj],   0.f);
      float v1f = fmaxf(a1[2*jj+1]*s1 + c1[2*jj+1], 0.f);
      pk[jj] = (u32)f2bf(v0f) | ((u32)f2bf(v1f)<<16);
    }
    __syncthreads();
    {
      uint4* dst = (uint4*)&T1[tid*72];
      #pragma unroll
      for(int q=0;q<8;q++) dst[q] = make_uint4(pk[4*q],pk[4*q+1],pk[4*q+2],pk[4*q+3]);
    }
    __syncthreads();
    #pragma unroll
    for(int ci=0; ci<2; ci++){
      int ch = (wid + 4*ci)*16 + l15;
      const u16* wb = W2t + (size_t)ch*64 + lg*8;
      bf16x8 b0 = *(const bf16x8*)(wb);
      bf16x8 b1 = *(const bf16x8*)(wb + 32);
      float a2v = a2[ch], c2v = c2[ch];
      for(int rt=0; rt<16; rt++){
        const u16* ap = T1 + (rt*16 + l15)*72 + lg*8;
        bf16x8 af0 = *(const bf16x8*)(ap);
        bf16x8 af1 = *(const bf16x8*)(ap + 32);
        f32x4 acc = {0.f,0.f,0.f,0.f};
        acc = __builtin_amdgcn_mfma_f32_16x16x32_bf16(af0, b0, acc, 0,0,0);
        acc = __builtin_amdgcn_mfma_f32_16x16x32_bf16(af1, b1, acc, 0,0,0);
        int rbase = rt*16 + lg*4;
        #pragma unroll
        for(int i=0;i<4;i++)
          T2[(rbase+i)*136 + ch] = f2bf(fmaxf(a2v*acc[i] + c2v, 0.f));
      }
    }
    __syncthreads();
    #pragma unroll
    for(int ci=0; ci<4; ci++){
      int ch = (wid + 4*ci)*16 + l15;
      const u16* wb = W3t + (size_t)ch*128 + lg*8;
      bf16x8 b[4];
      #pragma unroll
      for(int ks=0; ks<4; ks++) b[ks] = *(const bf16x8*)(wb + ks*32);
      for(int rt=0; rt<16; rt++){
        const u16* ap = T2 + (rt*16 + l15)*136 + lg*8;
        f32x4 acc = {0.f,0.f,0.f,0.f};
        #pragma unroll
        for(int ks=0; ks<4; ks++){
          bf16x8 af = *(const bf16x8*)(ap + ks*32);
          acc = __builtin_amdgcn_mfma_f32_16x16x32_bf16(af, b[ks], acc, 0,0,0);
        }
        #pragma unroll
        for(int i=0;i<4;i++){ s3[ci] += acc[i]; q3[ci] += acc[i]*acc[i]; }
      }
    }
  }
  #pragma unroll
  for(int ci=0; ci<4; ci++){
    float s = s3[ci], q = q3[ci];
    s += __shfl_xor(s,16); s += __shfl_xor(s,32);
    q += __shfl_xor(q,16); q += __shfl_xor(q,32);
    if(lg == 0){
      int ch = (wid + 4*ci)*16 + l15;
      atomicAdd(&sum3[ch], s);
      atomicAdd(&sq3[ch], q);
    }
  }
}

// ---------------- mega3: 64-pt tile, MFMA chain + sorted segmax + voxel GEMM ----
// LDS: X[0,42240) = T1[80][72] / T3[80][264]; Y[42240,65280) = T2[80][136] /
//      {Tz[80][72] @42240, TA[80][72] @53760}; vst[81] @65280; hdr @65616.
__global__ __launch_bounds__(256,2) void k_mega3(
    const float* __restrict__ pts, const u32* __restrict__ lin,
    const u32* __restrict__ counts, const float* __restrict__ vsum,
    const u32* __restrict__ offsets, const u32* __restrict__ order,
    const float* __restrict__ a0, const float* __restrict__ c0,
    const float* __restrict__ a1, const float* __restrict__ c1,
    const float* __restrict__ a2, const float* __restrict__ c2,
    const float* __restrict__ a3, const float* __restrict__ c3,
    const float* __restrict__ W1,
    const u16* __restrict__ W2t, const u16* __restrict__ W3t,
    const u16* __restrict__ W4t, const u16* __restrict__ Wct,
    const float* __restrict__ b4, const float* __restrict__ bc,
    u16* __restrict__ comp){
  __shared__ __align__(16) char SM[65664];
  u16* T1  = (u16*)(SM);
  u16* T3  = (u16*)(SM);
  u16* T2  = (u16*)(SM + 42240);
  u16* Tz  = (u16*)(SM + 42240);
  u16* TA  = (u16*)(SM + 53760);
  u32* vst = (u32*)(SM + 65280);   // [VCAP+1]
  u32* hdr = (u32*)(SM + 65616);   // [4]

  int tid = threadIdx.x, lane = tid & 63, wid = tid >> 6;
  int l15 = lane & 15, lg = lane >> 4;

  if(tid == 0){
    u32 t0 = (u32)blockIdx.x * 64u;
    u32 lo=0, hi=SS;
    while(lo<hi){ u32 mid=(lo+hi)>>1; if(offsets[mid] < t0) lo=mid+1; else hi=mid; }
    u32 vlo = lo, vhi;
    if(blockIdx.x == NB-1) vhi = SS;
    else {
      u32 t1 = t0 + 64u;
      lo = vlo; hi = SS;
      while(lo<hi){ u32 mid=(lo+hi)>>1; if(offsets[mid] < t1) lo=mid+1; else hi=mid; }
      vhi = lo;
    }
    hdr[0]=vlo; hdr[1]=vhi; hdr[2]=offsets[vlo]; hdr[3]=offsets[vhi];
  }
  __syncthreads();
  u32 vlo=hdr[0], vhi=hdr[1], start=hdr[2], end=hdr[3];
  int R = (int)(end - start); if(R > RCAP) R = RCAP;
  int V = (int)(vhi - vlo);   if(V > VCAP) V = VCAP;

  // per-voxel row ranges (complete segments; sorted order)
  if(tid <= VCAP){
    u32 o = (tid <= V) ? offsets[vlo + tid] : end;
    int s = (int)(o - start); if(s > RCAP) s = RCAP;
    vst[tid] = (u32)s;
  }

  // ---- feats + L1 scalar -> T1 ----
  for(int r=tid; r<RCAP; r+=256){
    uint4* dst = (uint4*)&T1[r*72];
    if(r < R){
      u32 p = order[start + r];
      float4 pt = ((const float4*)pts)[p];
      u32 v = lin[p];
      float cnt = fmaxf((float)counts[v], 1.0f);
      float inv = 1.0f/cnt;
      float mx = vsum[v*3+0]*inv, my = vsum[v*3+1]*inv, mz = vsum[v*3+2]*inv;
      float dist = sqrtf(pt.x*pt.x + pt.y*pt.y + pt.z*pt.z);
      float y0[8] = {pt.x, pt.y, pt.z, pt.w, dist, pt.x-mx, pt.y-my, pt.z-mz};
      #pragma unroll
      for(int k=0;k<8;k++) y0[k] = a0[k]*y0[k] + c0[k];
      u32 pk[32];
      #pragma unroll
      for(int jj=0; jj<32; jj++){
        float s0=0.f, s1=0.f;
        #pragma unroll
        for(int k=0;k<8;k++){ s0 += y0[k]*W1[k*64+2*jj]; s1 += y0[k]*W1[k*64+2*jj+1]; }
        float v0f = fmaxf(a1[2*jj]*s0   + c1[2*jj],   0.f);
        float v1f = fmaxf(a1[2*jj+1]*s1 + c1[2*jj+1], 0.f);
        pk[jj] = (u32)f2bf(v0f) | ((u32)f2bf(v1f)<<16);
      }
      #pragma unroll
      for(int q=0;q<8;q++) dst[q] = make_uint4(pk[4*q],pk[4*q+1],pk[4*q+2],pk[4*q+3]);
    } else {
      uint4 z = make_uint4(0,0,0,0);
      #pragma unroll
      for(int q=0;q<8;q++) dst[q] = z;
    }
  }
  __syncthreads();

  // ---- L2: T1(80x64) @ W2t -> bn2relu -> T2(80x128) ----
  for(int ci=0; ci<2; ci++){
    int ch = (wid + 4*ci)*16 + l15;
    const u16* wb = W2t + (size_t)ch*64 + lg*8;
    bf16x8 b0 = *(const bf16x8*)(wb);
    bf16x8 b1 = *(const bf16x8*)(wb + 32);
    float a2v = a2[ch], c2v = c2[ch];
    for(int rt=0; rt<5; rt++){
      const u16* ap = T1 + (rt*16 + l15)*72 + lg*8;
      bf16x8 af0 = *(const bf16x8*)(ap);
      bf16x8 af1 = *(const bf16x8*)(ap + 32);
      f32x4 acc = {0.f,0.f,0.f,0.f};
      acc = __builtin_amdgcn_mfma_f32_16x16x32_bf16(af0, b0, acc, 0,0,0);
      acc = __builtin_amdgcn_mfma_f32_16x16x32_bf16(af1, b1, acc, 0,0,0);
      int rbase = rt*16 + lg*4;
      #pragma unroll
      for(int i=0;i<4;i++)
        T2[(rbase+i)*136 + ch] = f2bf(fmaxf(a2v*acc[i] + c2v, 0.f));
    }
  }
  __syncthreads();

  // ---- L3: T2(80x128) @ W3t -> bn3relu -> T3(80x256) ----
  for(int ci=0; ci<4; ci++){
    int ch = (wid + 4*ci)*16 + l15;
    const u16* wb = W3t + (size_t)ch*128 + lg*8;
    bf16x8 b[4];
    #pragma unroll
    for(int ks=0; ks<4; ks++) b[ks] = *(const bf16x8*)(wb + ks*32);
    float a3v = a3[ch], c3v = c3[ch];
    for(int rt=0; rt<5; rt++){
      const u16* ap = T2 + (rt*16 + l15)*136 + lg*8;
      f32x4 acc = {0.f,0.f,0.f,0.f};
      #pragma unroll
      for(int ks=0; ks<4; ks++){
        bf16x8 af = *(const bf16x8*)(ap + ks*32);
        acc = __builtin_amdgcn_mfma_f32_16x16x32_bf16(af, b[ks], acc, 0,0,0);
      }
      int rbase = rt*16 + lg*4;
      #pragma unroll
      for(int i=0;i<4;i++)
        T3[(rbase+i)*264 + ch] = f2bf(fmaxf(a3v*acc[i] + c3v, 0.f));
    }
  }
  __syncthreads();

  // ---- L4 (64-col chunks): z4 -> Tz, sorted segmax -> TA, fused voxel GEMM ----
  f32x4 acc5[5];
  #pragma unroll
  for(int i=0;i<5;i++) acc5[i] = (f32x4){0.f,0.f,0.f,0.f};
  int ch4 = wid*16 + l15;

  for(int oc=0; oc<4; oc++){
    // z4 chunk: T3(80x256) @ W4t[:, oc*64+ch4] -> Tz bf16
    {
      int chg = oc*64 + ch4;
      const u16* wb = W4t + (size_t)chg*256 + lg*8;
      bf16x8 b[8];
      #pragma unroll
      for(int ks=0; ks<8; ks++) b[ks] = *(const bf16x8*)(wb + ks*32);
      for(int rt=0; rt<5; rt++){
        const u16* ap = T3 + (rt*16 + l15)*264 + lg*8;
        f32x4 acc = {0.f,0.f,0.f,0.f};
        #pragma unroll
        for(int ks=0; ks<8; ks++){
          bf16x8 af = *(const bf16x8*)(ap + ks*32);
          acc = __builtin_amdgcn_mfma_f32_16x16x32_bf16(af, b[ks], acc, 0,0,0);
        }
        int rbase = rt*16 + lg*4;
        #pragma unroll
        for(int i=0;i<4;i++)
          Tz[(rbase+i)*72 + ch4] = f2bf(acc[i]);
      }
    }
    __syncthreads();
    // sorted-segment max (bf16 RNE is monotone: max(round(x)) == round(max(x)))
    for(int i=tid; i<VCAP*64; i+=256){
      int v = i>>6, k = i&63;
      u32 r0 = vst[v], r1 = vst[v+1];
      u16 outv = 0;
      if(r1 > r0){
        float m = -3.0e38f;
        for(u32 r=r0; r<r1; r++) m = fmaxf(m, bf2f(Tz[r*72+k]));
        outv = f2bf(m + b4[oc*64+k]);
      }
      TA[v*72+k] = outv;
    }
    __syncthreads();
    // comp partial: TA(80x64) @ Wct[:, oc-chunk]
    {
      const u16* wb = Wct + (size_t)ch4*256 + oc*64 + lg*8;
      bf16x8 b0 = *(const bf16x8*)(wb);
      bf16x8 b1 = *(const bf16x8*)(wb + 32);
      #pragma unroll
      for(int vt=0; vt<5; vt++){
        const u16* ap = TA + (vt*16 + l15)*72 + lg*8;
        bf16x8 af0 = *(const bf16x8*)(ap);
        bf16x8 af1 = *(const bf16x8*)(ap + 32);
        acc5[vt] = __builtin_amdgcn_mfma_f32_16x16x32_bf16(af0, b0, acc5[vt], 0,0,0);
        acc5[vt] = __builtin_amdgcn_mfma_f32_16x16x32_bf16(af1, b1, acc5[vt], 0,0,0);
      }
    }
    __syncthreads();
  }

  // ---- comp write ----
  {
    float bcv = bc[ch4];
    #pragma unroll
    for(int vt=0; vt<5; vt++){
      int vbase = vt*16 + lg*4;
      #pragma unroll
      for(int i=0;i<4;i++){
        int vox = vbase + i;
        if(vox < V){
          bool nz = vst[vox+1] > vst[vox];
          float val = nz ? fmaxf(acc5[vt][i] + bcv, 0.f) : 0.f;
          comp[(size_t)(vlo+vox)*64 + ch4] = f2bf(val);
        }
      }
    }
  }
}

// ---------------- residual image from comp (proven) ----------------
__global__ __launch_bounds__(256) void k_resid(const u16* __restrict__ comp,
                                               float* __restrict__ out){
  __shared__ u32 cl[4*128*32];
  int t = threadIdx.x;
  int blk = blockIdx.x;
  int wq = blk & 3, h = (blk>>2) & 63, b = blk>>8;
  int w0 = wq*128;
  for(int fr=0; fr<4; fr++){
    const u32* src = (const u32*)comp + ((size_t)(((b*4+fr)*64 + h)*512 + w0))*32;
    for(int i=t; i<4096; i+=256){
      int vox = i>>5, wd = i&31;
      cl[fr*4096 + vox*32 + (wd ^ (vox&31))] = src[i];
    }
  }
  __syncthreads();
  int wl = t & 127, half = t >> 7;
  int mv = wl & 31;
  for(int ch = half; ch < 64; ch += 2){
    u32 wr3 = cl[3*4096 + wl*32 + ((ch>>1) ^ mv)];
    float r3 = bf2f((ch&1) ? (u16)(wr3>>16) : (u16)(wr3&0xFFFFu));
    #pragma unroll
    for(int fr=0; fr<3; fr++){
      u32 wrf = cl[fr*4096 + wl*32 + ((ch>>1) ^ mv)];
      float vf = bf2f((ch&1) ? (u16)(wrf>>16) : (u16)(wrf&0xFFFFu));
      out[(((size_t)(b*192 + fr*64 + ch))*64 + h)*512 + w0 + wl] = r3 - vf;
    }
  }
}

// ------------------------------- launcher -------------------------------------
extern "C" void kernel_launch(void* const* d_in, const int* in_sizes, int n_in,
                              void* d_out, int out_size, void* d_ws, size_t ws_size,
                              hipStream_t stream){
  const float* pts  = (const float*)d_in[0];
  const int*  coors = (const int*)d_in[1];
  const float* g0 = (const float*)d_in[2];
  const float* b0 = (const float*)d_in[3];
  const float* W1 = (const float*)d_in[4];
  const float* g1 = (const float*)d_in[5];
  const float* b1 = (const float*)d_in[6];
  const float* W2 = (const float*)d_in[7];
  const float* g2 = (const float*)d_in[8];
  const float* b2 = (const float*)d_in[9];
  const float* W3 = (const float*)d_in[10];
  const float* g3 = (const float*)d_in[11];
  const float* b3 = (const float*)d_in[12];
  const float* W4 = (const float*)d_in[13];
  const float* b4 = (const float*)d_in[14];
  const float* Wc = (const float*)d_in[15];
  const float* bc = (const float*)d_in[16];
  float* out = (float*)d_out;
  (void)in_sizes; (void)n_in; (void)out_size; (void)ws_size;

  char* ws = (char*)d_ws;
  size_t off = 0;
  auto alloc = [&](size_t bytes)->void*{
    void* p = ws + off;
    off += (bytes + 255) & ~(size_t)255;
    return p;
  };
  u32*  counts  = (u32*)alloc((size_t)SS*4);
  float* vsum   = (float*)alloc((size_t)SS*3*4);
  float* stats  = (float*)alloc(8192);
  size_t zero_bytes = off;
  u32*  lin     = (u32*)alloc((size_t)NPTS*4);
  u32*  offsets = (u32*)alloc((size_t)(SS+1)*4);
  u32*  cursor  = (u32*)alloc((size_t)SS*4);
  u32*  order   = (u32*)alloc((size_t)NPTS*4);
  u32*  blockSums = (u32*)alloc(1024);
  u16*  comp    = (u16*)alloc((size_t)SS*64*2);
  u16*  W2t = (u16*)alloc(8192*2);
  u16*  W3t = (u16*)alloc(32768*2);
  u16*  W4t = (u16*)alloc(65536*2);
  u16*  Wct = (u16*)alloc(16384*2);

  float* sum0=stats+0,   *sq0=stats+8,    *a0=stats+16,   *c0=stats+24;
  float* sum1=stats+32,  *sq1=stats+96,   *a1=stats+160,  *c1=stats+224;
  float* sum2=stats+288, *sq2=stats+416,  *a2=stats+544,  *c2=stats+672;
  float* sum3=stats+800, *sq3=stats+1056, *a3=stats+1312, *c3=stats+1568;

  hipMemsetAsync(d_ws, 0, zero_bytes, stream);

  k_prep   <<<480, 256,0,stream>>>(W2, W3, W4, Wc, W2t, W3t, W4t, Wct);
  k_lin    <<<2048,256,0,stream>>>(pts, coors, lin, counts, vsum);
  k_scan_a <<<256, 256,0,stream>>>(counts, blockSums);
  k_scan_b <<<1,   64, 0,stream>>>(blockSums);
  k_scan_c <<<256, 256,0,stream>>>(counts, blockSums, offsets, cursor);
  k_scatter<<<2048,256,0,stream>>>(lin, cursor, order);

  k_stats0 <<<2048,256,0,stream>>>(pts, lin, counts, vsum, sum0, sq0);
  k_fold   <<<1,   64, 0,stream>>>(sum0, sq0, g0, b0, a0, c0, 8);
  k_stats1 <<<2048,256,0,stream>>>(pts, lin, counts, vsum, a0, c0, W1, sum1, sq1);
  k_fold   <<<1,   64, 0,stream>>>(sum1, sq1, g1, b1, a1, c1, 64);
  k_mstats2<<<512, 256,0,stream>>>(pts, lin, counts, vsum, a0,c0,a1,c1, W1, W2t, sum2, sq2);
  k_fold   <<<2,   64, 0,stream>>>(sum2, sq2, g2, b2, a2, c2, 128);
  k_mstats3<<<512, 256,0,stream>>>(pts, lin, counts, vsum, a0,c0,a1,c1,a2,c2, W1, W2t, W3t, sum3, sq3);
  k_fold   <<<4,   64, 0,stream>>>(sum3, sq3, g3, b3, a3, c3, 256);

  k_mega3  <<<NB,  256,0,stream>>>(pts, lin, counts, vsum, offsets, order,
                                   a0,c0,a1,c1,a2,c2,a3,c3,
                                   W1, W2t, W3t, W4t, Wct, b4, bc, comp);
  k_resid  <<<512, 256,0,stream>>>(comp, out);
}

// Round 7
// 1190.544 us; speedup vs baseline: 11.0058x; 1.1056x over previous
//
#include <hip/hip_runtime.h>
#include <hip/hip_bf16.h>
#include <stdint.h>

typedef unsigned int u32;
typedef unsigned short u16;
typedef __attribute__((ext_vector_type(8))) short bf16x8;
typedef __attribute__((ext_vector_type(4))) float f32x4;

#define NPTS 524288
#define FF 4
#define HH 64
#define WW 512
#define SS 262144
#define EPSV 1e-5f
#define NB 8192      // 64 points per block
#define RCAP 80      // 64 + straddle slack
#define VCAP 80

__device__ __forceinline__ float bf2f(u16 h){ return __uint_as_float(((u32)h)<<16); }
__device__ __forceinline__ u16 f2bf(float f){
  u32 u = __float_as_uint(f);
  return (u16)((u + 0x7FFFu + ((u>>16)&1u)) >> 16);   // RNE (monotone)
}

__device__ __forceinline__ void point_feats(int p, const float* __restrict__ pts,
    const u32* __restrict__ lin, const u32* __restrict__ counts,
    const float* __restrict__ vsum, float f[8], u32* vout){
  float4 pt = ((const float4*)pts)[p];
  u32 v = lin[p];
  float cnt = fmaxf((float)counts[v], 1.0f);
  float inv = 1.0f/cnt;
  float mx = vsum[v*3+0]*inv, my = vsum[v*3+1]*inv, mz = vsum[v*3+2]*inv;
  float dist = sqrtf(pt.x*pt.x + pt.y*pt.y + pt.z*pt.z);
  f[0]=pt.x; f[1]=pt.y; f[2]=pt.z; f[3]=pt.w; f[4]=dist;
  f[5]=pt.x-mx; f[6]=pt.y-my; f[7]=pt.z-mz;
  *vout = v;
}

// ---------------- pass 1: linear voxel id + counts + coord sums ----------------
__global__ __launch_bounds__(256) void k_lin(const float* __restrict__ pts,
                                             const int* __restrict__ coors,
                                             u32* __restrict__ lin,
                                             u32* __restrict__ counts,
                                             float* __restrict__ vsum){
  int p = blockIdx.x*256 + threadIdx.x;
  int4 c = ((const int4*)coors)[p];
  u32 v = ((u32)((c.x*FF + c.y)*HH + c.z))*WW + (u32)c.w;
  lin[p] = v;
  atomicAdd(&counts[v], 1u);
  float4 pt = ((const float4*)pts)[p];
  atomicAdd(&vsum[v*3+0], pt.x);
  atomicAdd(&vsum[v*3+1], pt.y);
  atomicAdd(&vsum[v*3+2], pt.z);
}

// ---------------- counting-sort scan ----------------
__global__ __launch_bounds__(256) void k_scan_a(const u32* __restrict__ counts,
                                                u32* __restrict__ blockSums){
  __shared__ u32 lds[256];
  int b = blockIdx.x, t = threadIdx.x;
  uint4 c4 = ((const uint4*)counts)[b*256 + t];
  lds[t] = c4.x + c4.y + c4.z + c4.w;
  __syncthreads();
  for(int s=128; s>0; s>>=1){ if(t<s) lds[t] += lds[t+s]; __syncthreads(); }
  if(t==0) blockSums[b] = lds[0];
}

__global__ void k_scan_b(u32* blockSums){
  if(threadIdx.x==0){
    u32 run = 0;
    for(int i=0;i<256;i++){ u32 v = blockSums[i]; blockSums[i] = run; run += v; }
  }
}

__global__ __launch_bounds__(256) void k_scan_c(const u32* __restrict__ counts,
                                                const u32* __restrict__ blockSums,
                                                u32* __restrict__ offsets,
                                                u32* __restrict__ cursor){
  __shared__ u32 lds[256];
  int b = blockIdx.x, t = threadIdx.x;
  uint4 c4 = ((const uint4*)counts)[b*256 + t];
  u32 mysum = c4.x + c4.y + c4.z + c4.w;
  lds[t] = mysum;
  __syncthreads();
  for(int d=1; d<256; d<<=1){
    u32 v = (t>=d) ? lds[t-d] : 0u;
    __syncthreads();
    lds[t] += v;
    __syncthreads();
  }
  u32 off = blockSums[b] + (t>0 ? lds[t-1] : 0u);
  u32 base = (u32)(b*1024 + t*4);
  offsets[base+0]=off; cursor[base+0]=off; off += c4.x;
  offsets[base+1]=off; cursor[base+1]=off; off += c4.y;
  offsets[base+2]=off; cursor[base+2]=off; off += c4.z;
  offsets[base+3]=off; cursor[base+3]=off; off += c4.w;
  if(base+4 == SS) offsets[SS] = off;
}

__global__ __launch_bounds__(256) void k_scatter(const u32* __restrict__ lin,
                                                 u32* __restrict__ cursor,
                                                 u32* __restrict__ order){
  int p = blockIdx.x*256 + threadIdx.x;
  u32 v = lin[p];
  u32 pos = atomicAdd(&cursor[v], 1u);
  order[pos] = p;
}

// ---------------- weight prep: bf16 transposed ----------------
__global__ __launch_bounds__(256) void k_prep(const float* __restrict__ W2,
    const float* __restrict__ W3, const float* __restrict__ W4,
    const float* __restrict__ Wc,
    u16* __restrict__ W2t, u16* __restrict__ W3t, u16* __restrict__ W4t,
    u16* __restrict__ Wct){
  int i = blockIdx.x*256 + threadIdx.x;
  if(i < 8192){
    int k = i >> 7, n = i & 127;
    W2t[n*64 + k] = f2bf(W2[i]);
  } else if(i < 8192+32768){
    int j = i - 8192;
    int k = j >> 8, n = j & 255;
    W3t[n*128 + k] = f2bf(W3[j]);
  } else if(i < 8192+32768+65536){
    int j = i - (8192+32768);
    int k = j >> 8, n = j & 255;
    W4t[n*256 + k] = f2bf(W4[j]);
  } else if(i < 8192+32768+65536+16384){
    int j = i - (8192+32768+65536);
    int k = j >> 6, n = j & 63;
    Wct[n*256 + k] = f2bf(Wc[j]);
  }
}

// ---------------- stats0 (proven) ----------------
__global__ __launch_bounds__(256) void k_stats0(const float* __restrict__ pts,
    const u32* __restrict__ lin, const u32* __restrict__ counts,
    const float* __restrict__ vsum, float* __restrict__ sum0, float* __restrict__ sq0){
  int p = blockIdx.x*256 + threadIdx.x;
  float f[8]; u32 v;
  point_feats(p, pts, lin, counts, vsum, f, &v);
  __shared__ float lsum[4][8], lsq[4][8];
  int lane = threadIdx.x & 63, wv = threadIdx.x >> 6;
  #pragma unroll
  for(int c=0;c<8;c++){
    float s = f[c], q = f[c]*f[c];
    #pragma unroll
    for(int d=32; d; d>>=1){ s += __shfl_xor(s,d); q += __shfl_xor(q,d); }
    if(lane==0){ lsum[wv][c]=s; lsq[wv][c]=q; }
  }
  __syncthreads();
  if(threadIdx.x<8){
    float s=0.f,q=0.f;
    for(int g=0;g<4;g++){ s+=lsum[g][threadIdx.x]; q+=lsq[g][threadIdx.x]; }
    atomicAdd(&sum0[threadIdx.x], s);
    atomicAdd(&sq0[threadIdx.x], q);
  }
}

// ---------------- fold BN stats -> (a,c) (proven) ----------------
__global__ void k_fold(const float* __restrict__ sum, const float* __restrict__ sq,
                       const float* __restrict__ g, const float* __restrict__ b,
                       float* __restrict__ a, float* __restrict__ c, int C){
  int i = blockIdx.x*64 + threadIdx.x;
  if(i < C){
    float m = sum[i]*(1.0f/NPTS);
    float v = sq[i]*(1.0f/NPTS) - m*m;
    v = fmaxf(v, 0.0f);
    float ai = g[i] / sqrtf(v + EPSV);
    a[i] = ai;
    c[i] = b[i] - m*ai;
  }
}

// ---------------- stats1 (scalar, proven) ----------------
__global__ __launch_bounds__(256) void k_stats1(const float* __restrict__ pts,
    const u32* __restrict__ lin, const u32* __restrict__ counts,
    const float* __restrict__ vsum,
    const float* __restrict__ a0, const float* __restrict__ c0,
    const float* __restrict__ W1, float* __restrict__ sum1, float* __restrict__ sq1){
  __shared__ float ws[4][64], wq[4][64];
  int t = threadIdx.x;
  int p = blockIdx.x*256 + t;
  float f[8]; u32 v;
  point_feats(p, pts, lin, counts, vsum, f, &v);
  float y0[8];
  #pragma unroll
  for(int k=0;k<8;k++) y0[k] = a0[k]*f[k] + c0[k];
  float z[64];
  #pragma unroll
  for(int j=0;j<64;j++){
    float s=0.f;
    #pragma unroll
    for(int k=0;k<8;k++) s += y0[k]*W1[k*64+j];
    z[j]=s;
  }
  int lane = t&63, wv = t>>6;
  float ks=0.f, kq=0.f;
  #pragma unroll
  for(int c=0;c<64;c++){
    float s=z[c], q=z[c]*z[c];
    #pragma unroll
    for(int d=1; d<64; d<<=1){ s+=__shfl_xor(s,d); q+=__shfl_xor(q,d); }
    if(lane==c){ ks=s; kq=q; }
  }
  ws[wv][lane]=ks; wq[wv][lane]=kq;
  __syncthreads();
  if(t<64){
    float S=ws[0][t]+ws[1][t]+ws[2][t]+ws[3][t];
    float Q=wq[0][t]+wq[1][t]+wq[2][t]+wq[3][t];
    atomicAdd(&sum1[t],S); atomicAdd(&sq1[t],Q);
  }
}

// ---------------- mstats2: z2 stats via MFMA (proven) ----------
__global__ __launch_bounds__(256,2) void k_mstats2(
    const float* __restrict__ pts, const u32* __restrict__ lin,
    const u32* __restrict__ counts, const float* __restrict__ vsum,
    const float* __restrict__ a0, const float* __restrict__ c0,
    const float* __restrict__ a1, const float* __restrict__ c1,
    const float* __restrict__ W1, const u16* __restrict__ W2t,
    float* __restrict__ sum2, float* __restrict__ sq2){
  __shared__ u16 T1[256*72];
  int tid = threadIdx.x, lane = tid&63, wid = tid>>6, l15 = lane&15, lg = lane>>4;
  float s2[2] = {0.f,0.f}, q2[2] = {0.f,0.f};

  for(int cch=0; cch<4; cch++){
    int p = blockIdx.x*1024 + cch*256 + tid;
    float f[8]; u32 v;
    point_feats(p, pts, lin, counts, vsum, f, &v);
    float y0[8];
    #pragma unroll
    for(int k=0;k<8;k++) y0[k] = a0[k]*f[k] + c0[k];
    u32 pk[32];
    #pragma unroll
    for(int jj=0;jj<32;jj++){
      float s0=0.f, s1=0.f;
      #pragma unroll
      for(int k=0;k<8;k++){ s0 += y0[k]*W1[k*64+2*jj]; s1 += y0[k]*W1[k*64+2*jj+1]; }
      float v0f = fmaxf(a1[2*jj]*s0   + c1[2*jj],   0.f);
      float v1f = fmaxf(a1[2*jj+1]*s1 + c1[2*jj+1], 0.f);
      pk[jj] = (u32)f2bf(v0f) | ((u32)f2bf(v1f)<<16);
    }
    __syncthreads();
    {
      uint4* dst = (uint4*)&T1[tid*72];
      #pragma unroll
      for(int q=0;q<8;q++) dst[q] = make_uint4(pk[4*q],pk[4*q+1],pk[4*q+2],pk[4*q+3]);
    }
    __syncthreads();
    #pragma unroll
    for(int ci=0; ci<2; ci++){
      int ch = (wid + 4*ci)*16 + l15;
      const u16* wb = W2t + (size_t)ch*64 + lg*8;
      bf16x8 b0 = *(const bf16x8*)(wb);
      bf16x8 b1 = *(const bf16x8*)(wb + 32);
      for(int rt=0; rt<16; rt++){
        const u16* ap = T1 + (rt*16 + l15)*72 + lg*8;
        bf16x8 af0 = *(const bf16x8*)(ap);
        bf16x8 af1 = *(const bf16x8*)(ap + 32);
        f32x4 acc = {0.f,0.f,0.f,0.f};
        acc = __builtin_amdgcn_mfma_f32_16x16x32_bf16(af0, b0, acc, 0,0,0);
        acc = __builtin_amdgcn_mfma_f32_16x16x32_bf16(af1, b1, acc, 0,0,0);
        #pragma unroll
        for(int i=0;i<4;i++){ s2[ci] += acc[i]; q2[ci] += acc[i]*acc[i]; }
      }
    }
  }
  #pragma unroll
  for(int ci=0; ci<2; ci++){
    float s = s2[ci], q = q2[ci];
    s += __shfl_xor(s,16); s += __shfl_xor(s,32);
    q += __shfl_xor(q,16); q += __shfl_xor(q,32);
    if(lg == 0){
      int ch = (wid + 4*ci)*16 + l15;
      atomicAdd(&sum2[ch], s);
      atomicAdd(&sq2[ch], q);
    }
  }
}

// ---------------- chain2: sorted-order chain, z3 stats + y2s dump ----------------
// Identical math to proven mstats3, but rows are sorted positions (gather via
// order[]) and the T2 tile (y2, bf16, post-bn2relu) is dumped to HBM so mega4
// never recomputes L1/L2. Stats accumulation is order-independent.
__global__ __launch_bounds__(256,1) void k_chain2(
    const float* __restrict__ pts, const u32* __restrict__ lin,
    const u32* __restrict__ counts, const float* __restrict__ vsum,
    const u32* __restrict__ order,
    const float* __restrict__ a0, const float* __restrict__ c0,
    const float* __restrict__ a1, const float* __restrict__ c1,
    const float* __restrict__ a2, const float* __restrict__ c2,
    const float* __restrict__ W1, const u16* __restrict__ W2t,
    const u16* __restrict__ W3t,
    u32* __restrict__ y2s,
    float* __restrict__ sum3, float* __restrict__ sq3){
  __shared__ u16 T1[256*72];
  __shared__ u16 T2[256*136];
  int tid = threadIdx.x, lane = tid&63, wid = tid>>6, l15 = lane&15, lg = lane>>4;
  float s3[4] = {0.f,0.f,0.f,0.f}, q3[4] = {0.f,0.f,0.f,0.f};

  for(int cch=0; cch<4; cch++){
    int rr = blockIdx.x*1024 + cch*256 + tid;   // sorted row index
    int p = (int)order[rr];
    float f[8]; u32 v;
    point_feats(p, pts, lin, counts, vsum, f, &v);
    float y0[8];
    #pragma unroll
    for(int k=0;k<8;k++) y0[k] = a0[k]*f[k] + c0[k];
    u32 pk[32];
    #pragma unroll
    for(int jj=0;jj<32;jj++){
      float s0=0.f, s1=0.f;
      #pragma unroll
      for(int k=0;k<8;k++){ s0 += y0[k]*W1[k*64+2*jj]; s1 += y0[k]*W1[k*64+2*jj+1]; }
      float v0f = fmaxf(a1[2*jj]*s0   + c1[2*jj],   0.f);
      float v1f = fmaxf(a1[2*jj+1]*s1 + c1[2*jj+1], 0.f);
      pk[jj] = (u32)f2bf(v0f) | ((u32)f2bf(v1f)<<16);
    }
    __syncthreads();
    {
      uint4* dst = (uint4*)&T1[tid*72];
      #pragma unroll
      for(int q=0;q<8;q++) dst[q] = make_uint4(pk[4*q],pk[4*q+1],pk[4*q+2],pk[4*q+3]);
    }
    __syncthreads();
    // L2: T1(256x64) @ W2t -> bn2relu -> T2(256x128)
    #pragma unroll
    for(int ci=0; ci<2; ci++){
      int ch = (wid + 4*ci)*16 + l15;
      const u16* wb = W2t + (size_t)ch*64 + lg*8;
      bf16x8 b0 = *(const bf16x8*)(wb);
      bf16x8 b1 = *(const bf16x8*)(wb + 32);
      float a2v = a2[ch], c2v = c2[ch];
      for(int rt=0; rt<16; rt++){
        const u16* ap = T1 + (rt*16 + l15)*72 + lg*8;
        bf16x8 af0 = *(const bf16x8*)(ap);
        bf16x8 af1 = *(const bf16x8*)(ap + 32);
        f32x4 acc = {0.f,0.f,0.f,0.f};
        acc = __builtin_amdgcn_mfma_f32_16x16x32_bf16(af0, b0, acc, 0,0,0);
        acc = __builtin_amdgcn_mfma_f32_16x16x32_bf16(af1, b1, acc, 0,0,0);
        int rbase = rt*16 + lg*4;
        #pragma unroll
        for(int i=0;i<4;i++)
          T2[(rbase+i)*136 + ch] = f2bf(fmaxf(a2v*acc[i] + c2v, 0.f));
      }
    }
    __syncthreads();
    // dump y2 tile (sorted rows) to HBM: 256 rows x 64 u32 words
    {
      const u32* T2w = (const u32*)T2;
      u32 base = (u32)blockIdx.x*1024u + (u32)cch*256u;
      for(int i=tid; i<256*64; i+=256){
        int row = i>>6, w = i&63;
        y2s[(size_t)(base+row)*64 + w] = T2w[row*68 + w];
      }
    }
    // L3: z3 = T2(256x128) @ W3t, accumulate sum/sumsq only
    #pragma unroll
    for(int ci=0; ci<4; ci++){
      int ch = (wid + 4*ci)*16 + l15;
      const u16* wb = W3t + (size_t)ch*128 + lg*8;
      bf16x8 b[4];
      #pragma unroll
      for(int ks=0; ks<4; ks++) b[ks] = *(const bf16x8*)(wb + ks*32);
      for(int rt=0; rt<16; rt++){
        const u16* ap = T2 + (rt*16 + l15)*136 + lg*8;
        f32x4 acc = {0.f,0.f,0.f,0.f};
        #pragma unroll
        for(int ks=0; ks<4; ks++){
          bf16x8 af = *(const bf16x8*)(ap + ks*32);
          acc = __builtin_amdgcn_mfma_f32_16x16x32_bf16(af, b[ks], acc, 0,0,0);
        }
        #pragma unroll
        for(int i=0;i<4;i++){ s3[ci] += acc[i]; q3[ci] += acc[i]*acc[i]; }
      }
    }
  }
  #pragma unroll
  for(int ci=0; ci<4; ci++){
    float s = s3[ci], q = q3[ci];
    s += __shfl_xor(s,16); s += __shfl_xor(s,32);
    q += __shfl_xor(q,16); q += __shfl_xor(q,32);
    if(lg == 0){
      int ch = (wid + 4*ci)*16 + l15;
      atomicAdd(&sum3[ch], s);
      atomicAdd(&sq3[ch], q);
    }
  }
}

// ---------------- mega4: stage y2s -> L3 -> L4 + sorted segmax + voxel GEMM ----
// LDS: T3[80][264] @0 (42240); union @42240: T2s[80][136] (21760, dead after L3)
//      / {Tz[80][72] @42240, TA[80][72] @53760}; vst[81] @65280; hdr @65616.
__global__ __launch_bounds__(256,2) void k_mega4(
    const u32* __restrict__ offsets, const u32* __restrict__ y2s,
    const float* __restrict__ a3, const float* __restrict__ c3,
    const u16* __restrict__ W3t, const u16* __restrict__ W4t,
    const u16* __restrict__ Wct,
    const float* __restrict__ b4, const float* __restrict__ bc,
    u16* __restrict__ comp){
  __shared__ __align__(16) char SM[65664];
  u16* T3  = (u16*)(SM);
  u16* T2s = (u16*)(SM + 42240);
  u16* Tz  = (u16*)(SM + 42240);
  u16* TA  = (u16*)(SM + 53760);
  u32* vst = (u32*)(SM + 65280);   // [VCAP+1]
  u32* hdr = (u32*)(SM + 65616);   // [4]

  int tid = threadIdx.x, lane = tid & 63, wid = tid >> 6;
  int l15 = lane & 15, lg = lane >> 4;

  if(tid == 0){
    u32 t0 = (u32)blockIdx.x * 64u;
    u32 lo=0, hi=SS;
    while(lo<hi){ u32 mid=(lo+hi)>>1; if(offsets[mid] < t0) lo=mid+1; else hi=mid; }
    u32 vlo = lo, vhi;
    if(blockIdx.x == NB-1) vhi = SS;
    else {
      u32 t1 = t0 + 64u;
      lo = vlo; hi = SS;
      while(lo<hi){ u32 mid=(lo+hi)>>1; if(offsets[mid] < t1) lo=mid+1; else hi=mid; }
      vhi = lo;
    }
    hdr[0]=vlo; hdr[1]=vhi; hdr[2]=offsets[vlo]; hdr[3]=offsets[vhi];
  }
  __syncthreads();
  u32 vlo=hdr[0], vhi=hdr[1], start=hdr[2], end=hdr[3];
  int R = (int)(end - start); if(R > RCAP) R = RCAP;
  int V = (int)(vhi - vlo);   if(V > VCAP) V = VCAP;

  // per-voxel row ranges (complete segments; sorted order)
  if(tid <= VCAP){
    u32 o = (tid <= V) ? offsets[vlo + tid] : end;
    int s = (int)(o - start); if(s > RCAP) s = RCAP;
    vst[tid] = (u32)s;
  }

  // ---- stage y2s rows -> T2s (zero pad rows >= R) ----
  {
    u32* T2w = (u32*)T2s;
    for(int i=tid; i<RCAP*64; i+=256){
      int row = i>>6, w = i&63;
      u32 val = (row < R) ? y2s[(size_t)(start+row)*64 + w] : 0u;
      T2w[row*68 + w] = val;
    }
  }
  __syncthreads();

  // ---- L3: T2s(80x128) @ W3t -> bn3relu -> T3(80x256) ----
  for(int ci=0; ci<4; ci++){
    int ch = (wid + 4*ci)*16 + l15;
    const u16* wb = W3t + (size_t)ch*128 + lg*8;
    bf16x8 b[4];
    #pragma unroll
    for(int ks=0; ks<4; ks++) b[ks] = *(const bf16x8*)(wb + ks*32);
    float a3v = a3[ch], c3v = c3[ch];
    for(int rt=0; rt<5; rt++){
      const u16* ap = T2s + (rt*16 + l15)*136 + lg*8;
      f32x4 acc = {0.f,0.f,0.f,0.f};
      #pragma unroll
      for(int ks=0; ks<4; ks++){
        bf16x8 af = *(const bf16x8*)(ap + ks*32);
        acc = __builtin_amdgcn_mfma_f32_16x16x32_bf16(af, b[ks], acc, 0,0,0);
      }
      int rbase = rt*16 + lg*4;
      #pragma unroll
      for(int i=0;i<4;i++)
        T3[(rbase+i)*264 + ch] = f2bf(fmaxf(a3v*acc[i] + c3v, 0.f));
    }
  }
  __syncthreads();

  // ---- L4 (64-col chunks): z4 -> Tz, sorted segmax -> TA, fused voxel GEMM ----
  f32x4 acc5[5];
  #pragma unroll
  for(int i=0;i<5;i++) acc5[i] = (f32x4){0.f,0.f,0.f,0.f};
  int ch4 = wid*16 + l15;

  for(int oc=0; oc<4; oc++){
    // z4 chunk: T3(80x256) @ W4t[:, oc*64+ch4] -> Tz bf16
    {
      int chg = oc*64 + ch4;
      const u16* wb = W4t + (size_t)chg*256 + lg*8;
      bf16x8 b[8];
      #pragma unroll
      for(int ks=0; ks<8; ks++) b[ks] = *(const bf16x8*)(wb + ks*32);
      for(int rt=0; rt<5; rt++){
        const u16* ap = T3 + (rt*16 + l15)*264 + lg*8;
        f32x4 acc = {0.f,0.f,0.f,0.f};
        #pragma unroll
        for(int ks=0; ks<8; ks++){
          bf16x8 af = *(const bf16x8*)(ap + ks*32);
          acc = __builtin_amdgcn_mfma_f32_16x16x32_bf16(af, b[ks], acc, 0,0,0);
        }
        int rbase = rt*16 + lg*4;
        #pragma unroll
        for(int i=0;i<4;i++)
          Tz[(rbase+i)*72 + ch4] = f2bf(acc[i]);
      }
    }
    __syncthreads();
    // sorted-segment max (bf16 RNE is monotone: max(round(x)) == round(max(x)))
    for(int i=tid; i<VCAP*64; i+=256){
      int v = i>>6, k = i&63;
      u32 r0 = vst[v], r1 = vst[v+1];
      u16 outv = 0;
      if(r1 > r0){
        float m = -3.0e38f;
        for(u32 r=r0; r<r1; r++) m = fmaxf(m, bf2f(Tz[r*72+k]));
        outv = f2bf(m + b4[oc*64+k]);
      }
      TA[v*72+k] = outv;
    }
    __syncthreads();
    // comp partial: TA(80x64) @ Wct[:, oc-chunk]
    {
      const u16* wb = Wct + (size_t)ch4*256 + oc*64 + lg*8;
      bf16x8 b0 = *(const bf16x8*)(wb);
      bf16x8 b1 = *(const bf16x8*)(wb + 32);
      #pragma unroll
      for(int vt=0; vt<5; vt++){
        const u16* ap = TA + (vt*16 + l15)*72 + lg*8;
        bf16x8 af0 = *(const bf16x8*)(ap);
        bf16x8 af1 = *(const bf16x8*)(ap + 32);
        acc5[vt] = __builtin_amdgcn_mfma_f32_16x16x32_bf16(af0, b0, acc5[vt], 0,0,0);
        acc5[vt] = __builtin_amdgcn_mfma_f32_16x16x32_bf16(af1, b1, acc5[vt], 0,0,0);
      }
    }
    __syncthreads();
  }

  // ---- comp write ----
  {
    float bcv = bc[ch4];
    #pragma unroll
    for(int vt=0; vt<5; vt++){
      int vbase = vt*16 + lg*4;
      #pragma unroll
      for(int i=0;i<4;i++){
        int vox = vbase + i;
        if(vox < V){
          bool nz = vst[vox+1] > vst[vox];
          float val = nz ? fmaxf(acc5[vt][i] + bcv, 0.f) : 0.f;
          comp[(size_t)(vlo+vox)*64 + ch4] = f2bf(val);
        }
      }
    }
  }
}

// ---------------- residual image from comp (proven) ----------------
__global__ __launch_bounds__(256) void k_resid(const u16* __restrict__ comp,
                                               float* __restrict__ out){
  __shared__ u32 cl[4*128*32];
  int t = threadIdx.x;
  int blk = blockIdx.x;
  int wq = blk & 3, h = (blk>>2) & 63, b = blk>>8;
  int w0 = wq*128;
  for(int fr=0; fr<4; fr++){
    const u32* src = (const u32*)comp + ((size_t)(((b*4+fr)*64 + h)*512 + w0))*32;
    for(int i=t; i<4096; i+=256){
      int vox = i>>5, wd = i&31;
      cl[fr*4096 + vox*32 + (wd ^ (vox&31))] = src[i];
    }
  }
  __syncthreads();
  int wl = t & 127, half = t >> 7;
  int mv = wl & 31;
  for(int ch = half; ch < 64; ch += 2){
    u32 wr3 = cl[3*4096 + wl*32 + ((ch>>1) ^ mv)];
    float r3 = bf2f((ch&1) ? (u16)(wr3>>16) : (u16)(wr3&0xFFFFu));
    #pragma unroll
    for(int fr=0; fr<3; fr++){
      u32 wrf = cl[fr*4096 + wl*32 + ((ch>>1) ^ mv)];
      float vf = bf2f((ch&1) ? (u16)(wrf>>16) : (u16)(wrf&0xFFFFu));
      out[(((size_t)(b*192 + fr*64 + ch))*64 + h)*512 + w0 + wl] = r3 - vf;
    }
  }
}

// ------------------------------- launcher -------------------------------------
extern "C" void kernel_launch(void* const* d_in, const int* in_sizes, int n_in,
                              void* d_out, int out_size, void* d_ws, size_t ws_size,
                              hipStream_t stream){
  const float* pts  = (const float*)d_in[0];
  const int*  coors = (const int*)d_in[1];
  const float* g0 = (const float*)d_in[2];
  const float* b0 = (const float*)d_in[3];
  const float* W1 = (const float*)d_in[4];
  const float* g1 = (const float*)d_in[5];
  const float* b1 = (const float*)d_in[6];
  const float* W2 = (const float*)d_in[7];
  const float* g2 = (const float*)d_in[8];
  const float* b2 = (const float*)d_in[9];
  const float* W3 = (const float*)d_in[10];
  const float* g3 = (const float*)d_in[11];
  const float* b3 = (const float*)d_in[12];
  const float* W4 = (const float*)d_in[13];
  const float* b4 = (const float*)d_in[14];
  const float* Wc = (const float*)d_in[15];
  const float* bc = (const float*)d_in[16];
  float* out = (float*)d_out;
  (void)in_sizes; (void)n_in; (void)out_size; (void)ws_size;

  char* ws = (char*)d_ws;
  size_t off = 0;
  auto alloc = [&](size_t bytes)->void*{
    void* p = ws + off;
    off += (bytes + 255) & ~(size_t)255;
    return p;
  };
  u32*  counts  = (u32*)alloc((size_t)SS*4);
  float* vsum   = (float*)alloc((size_t)SS*3*4);
  float* stats  = (float*)alloc(8192);
  size_t zero_bytes = off;
  u32*  lin     = (u32*)alloc((size_t)NPTS*4);
  u32*  offsets = (u32*)alloc((size_t)(SS+1)*4);
  u32*  cursor  = (u32*)alloc((size_t)SS*4);
  u32*  order   = (u32*)alloc((size_t)NPTS*4);
  u32*  blockSums = (u32*)alloc(1024);
  u16*  comp    = (u16*)alloc((size_t)SS*64*2);
  u16*  W2t = (u16*)alloc(8192*2);
  u16*  W3t = (u16*)alloc(32768*2);
  u16*  W4t = (u16*)alloc(65536*2);
  u16*  Wct = (u16*)alloc(16384*2);
  u32*  y2s = (u32*)alloc((size_t)NPTS*64*4);   // y2 bf16, sorted rows (134 MB)

  float* sum0=stats+0,   *sq0=stats+8,    *a0=stats+16,   *c0=stats+24;
  float* sum1=stats+32,  *sq1=stats+96,   *a1=stats+160,  *c1=stats+224;
  float* sum2=stats+288, *sq2=stats+416,  *a2=stats+544,  *c2=stats+672;
  float* sum3=stats+800, *sq3=stats+1056, *a3=stats+1312, *c3=stats+1568;

  hipMemsetAsync(d_ws, 0, zero_bytes, stream);

  k_prep   <<<480, 256,0,stream>>>(W2, W3, W4, Wc, W2t, W3t, W4t, Wct);
  k_lin    <<<2048,256,0,stream>>>(pts, coors, lin, counts, vsum);
  k_scan_a <<<256, 256,0,stream>>>(counts, blockSums);
  k_scan_b <<<1,   64, 0,stream>>>(blockSums);
  k_scan_c <<<256, 256,0,stream>>>(counts, blockSums, offsets, cursor);
  k_scatter<<<2048,256,0,stream>>>(lin, cursor, order);

  k_stats0 <<<2048,256,0,stream>>>(pts, lin, counts, vsum, sum0, sq0);
  k_fold   <<<1,   64, 0,stream>>>(sum0, sq0, g0, b0, a0, c0, 8);
  k_stats1 <<<2048,256,0,stream>>>(pts, lin, counts, vsum, a0, c0, W1, sum1, sq1);
  k_fold   <<<1,   64, 0,stream>>>(sum1, sq1, g1, b1, a1, c1, 64);
  k_mstats2<<<512, 256,0,stream>>>(pts, lin, counts, vsum, a0,c0,a1,c1, W1, W2t, sum2, sq2);
  k_fold   <<<2,   64, 0,stream>>>(sum2, sq2, g2, b2, a2, c2, 128);
  k_chain2 <<<512, 256,0,stream>>>(pts, lin, counts, vsum, order,
                                   a0,c0,a1,c1,a2,c2, W1, W2t, W3t,
                                   y2s, sum3, sq3);
  k_fold   <<<4,   64, 0,stream>>>(sum3, sq3, g3, b3, a3, c3, 256);

  k_mega4  <<<NB,  256,0,stream>>>(offsets, y2s, a3,c3, W3t, W4t, Wct, b4, bc, comp);
  k_resid  <<<512, 256,0,stream>>>(comp, out);
}